// Round 1
// baseline (649.145 us; speedup 1.0000x reference)
//
#include <hip/hip_runtime.h>
#include <hip/hip_bf16.h>

#define NLVL 16
#define TSZ  16384
#define ZDIM 512
#define SDIM 256
#define IMG  256
#define HID  64
#define FDIM 32
#define NB   8

// floor(16 * exp(l*ln(16)/15)) computed with exact fp64 rounding analysis:
// l=15 lands at 255.99999999999997 -> 255 (NOT 256).
__device__ constexpr float RES_TAB[16] = {
  16.f, 19.f, 23.f, 27.f, 33.f, 40.f, 48.f, 58.f,
  70.f, 84.f, 101.f, 122.f, 147.f, 176.f, 212.f, 255.f
};

__device__ __forceinline__ float lrelu(float x) {
  float v = x < 0.0f ? 0.2f * x : x;
  return 1.41421356237309515f * v;  // GAIN * where(x>=0, x, 0.2x)
}

// ws layout (floats):
//   [0      .. 16384)  W0T[b][j<64][i<32]  (scale*style0*w0*demod0 folded)
//   [16384  .. 49152)  W1T[b][j<64][i<64]
//   [49152  .. 51200)  W2T[b][c<4][i<64]   (c==3 row zero-padded)
//   [51200  .. 51200+65536*32)  g[n][32]   (batch-independent hash features)

__global__ void __launch_bounds__(1024) k_setup(
    const float* __restrict__ z,
    const float* __restrict__ mw0, const float* __restrict__ mb0,
    const float* __restrict__ mw1, const float* __restrict__ mb1,
    const float* __restrict__ mw2, const float* __restrict__ mb2,
    const float* __restrict__ w_mod, const float* __restrict__ b_mod,
    const float* __restrict__ a0w, const float* __restrict__ a0b,
    const float* __restrict__ w0,
    const float* __restrict__ a1w, const float* __restrict__ a1b,
    const float* __restrict__ w1,
    const float* __restrict__ a2w, const float* __restrict__ a2b,
    const float* __restrict__ w2,
    float* __restrict__ ws)
{
  __shared__ float zs[NB][ZDIM];        // 16 KB
  __shared__ float sA[NB][SDIM];        // 8 KB
  __shared__ float sB[NB][SDIM];        // 8 KB
  __shared__ float st0[NB][FDIM], scf[NB][FDIM];
  __shared__ float st1[NB][HID], st2[NB][HID];
  __shared__ float dm0[NB][HID], dm1[NB][HID], dm2[NB][4];

  const int t = threadIdx.x;

  for (int k = t; k < NB * ZDIM; k += 1024) zs[k >> 9][k & 511] = z[k];
  __syncthreads();

  // mapping layer 0: z(8x512) @ mw0(512x256) + mb0, lrelu
  {
    int j = t & 255, bq = t >> 8;
    int b0 = 2 * bq, b1 = 2 * bq + 1;
    float acc0 = mb0[j], acc1 = acc0;
    for (int k = 0; k < ZDIM; ++k) {
      float w = mw0[k * SDIM + j];
      acc0 = fmaf(zs[b0][k], w, acc0);
      acc1 = fmaf(zs[b1][k], w, acc1);
    }
    sA[b0][j] = lrelu(acc0);
    sA[b1][j] = lrelu(acc1);
  }
  __syncthreads();
  // mapping layer 1
  {
    int j = t & 255, bq = t >> 8;
    int b0 = 2 * bq, b1 = 2 * bq + 1;
    float acc0 = mb1[j], acc1 = acc0;
    for (int k = 0; k < SDIM; ++k) {
      float w = mw1[k * SDIM + j];
      acc0 = fmaf(sA[b0][k], w, acc0);
      acc1 = fmaf(sA[b1][k], w, acc1);
    }
    sB[b0][j] = lrelu(acc0);
    sB[b1][j] = lrelu(acc1);
  }
  __syncthreads();
  // mapping layer 2 -> s in sA
  {
    int j = t & 255, bq = t >> 8;
    int b0 = 2 * bq, b1 = 2 * bq + 1;
    float acc0 = mb2[j], acc1 = acc0;
    for (int k = 0; k < SDIM; ++k) {
      float w = mw2[k * SDIM + j];
      acc0 = fmaf(sB[b0][k], w, acc0);
      acc1 = fmaf(sB[b1][k], w, acc1);
    }
    sA[b0][j] = lrelu(acc0);
    sA[b1][j] = lrelu(acc1);
  }
  __syncthreads();

  // scale (1 + s@w_mod + b_mod) and style0 (s@a0w + a0b): 8*32 entries
  if (t < 256) {
    int b = t >> 5, i = t & 31;
    float am = b_mod[i], as = a0b[i];
    for (int k = 0; k < SDIM; ++k) {
      float sv = sA[b][k];
      am = fmaf(sv, w_mod[k * FDIM + i], am);
      as = fmaf(sv, a0w[k * FDIM + i], as);
    }
    scf[b][i] = 1.0f + am;
    st0[b][i] = as;
  }
  // style1, style2: 8*64 entries
  if (t < 512) {
    int b = t >> 6, j = t & 63;
    float v1 = a1b[j], v2 = a2b[j];
    for (int k = 0; k < SDIM; ++k) {
      float sv = sA[b][k];
      v1 = fmaf(sv, a1w[k * HID + j], v1);
      v2 = fmaf(sv, a2w[k * HID + j], v2);
    }
    st1[b][j] = v1;
    st2[b][j] = v2;
  }
  __syncthreads();

  // demods: rsqrt(sum_i (style_i*w_ij)^2 + 1e-8)
  if (t < 512) {
    int b = t >> 6, j = t & 63;
    float acc = 1e-8f;
    for (int i = 0; i < FDIM; ++i) { float p = st0[b][i] * w0[i * HID + j]; acc = fmaf(p, p, acc); }
    dm0[b][j] = 1.0f / sqrtf(acc);
    float ac1 = 1e-8f;
    for (int i = 0; i < HID; ++i) { float p = st1[b][i] * w1[i * HID + j]; ac1 = fmaf(p, p, ac1); }
    dm1[b][j] = 1.0f / sqrtf(ac1);
  }
  if (t < 32) {
    int b = t >> 2, c = t & 3;
    if (c < 3) {
      float acc = 1e-8f;
      for (int i = 0; i < HID; ++i) { float p = st2[b][i] * w2[i * 3 + c]; acc = fmaf(p, p, acc); }
      dm2[b][c] = 1.0f / sqrtf(acc);
    } else {
      dm2[b][c] = 0.0f;
    }
  }
  __syncthreads();

  // effective weights (transposed [out][in] rows, contiguous in input idx)
  for (int f = t; f < 16384; f += 1024) {
    int b = f >> 11, j = (f >> 5) & 63, i = f & 31;
    ws[f] = scf[b][i] * st0[b][i] * w0[i * HID + j] * dm0[b][j];
  }
  for (int f = t; f < 32768; f += 1024) {
    int b = f >> 12, j = (f >> 6) & 63, i = f & 63;
    ws[16384 + f] = st1[b][i] * w1[i * HID + j] * dm1[b][j];
  }
  for (int f = t; f < 2048; f += 1024) {
    int b = f >> 8, c = (f >> 6) & 3, i = f & 63;
    ws[49152 + f] = (c < 3) ? st2[b][i] * w2[i * 3 + c] * dm2[b][c] : 0.0f;
  }
}

// batch-independent hash-grid features for pixel n
__device__ __forceinline__ void hash_features(const float* __restrict__ bt,
                                              int n, float* g)
{
  const float inv = 1.0f / 256.0f;
  float cx = ((n >> 8) + 0.5f) * inv;
  float cy = ((n & 255) + 0.5f) * inv;
#pragma unroll
  for (int l = 0; l < NLVL; ++l) {
    float res = RES_TAB[l];
    float px = cx * res, py = cy * res;
    float fx0 = floorf(px), fy0 = floorf(py);
    float fx = px - fx0, fy = py - fy0;
    unsigned x0 = (unsigned)fx0, y0 = (unsigned)fy0;
    unsigned hy0 = y0 * 2654435761u;
    unsigned hy1 = (y0 + 1u) * 2654435761u;
    unsigned i00 = (x0 ^ hy0) & 16383u;
    unsigned i10 = ((x0 + 1u) ^ hy0) & 16383u;
    unsigned i01 = (x0 ^ hy1) & 16383u;
    unsigned i11 = ((x0 + 1u) ^ hy1) & 16383u;
    const float2* tb = (const float2*)(bt + (size_t)l * (TSZ * 2));
    float2 f00 = tb[i00], f10 = tb[i10], f01 = tb[i01], f11 = tb[i11];
    float wx0 = 1.0f - fx, wy0 = 1.0f - fy;
    float w00 = wx0 * wy0, w10 = fx * wy0, w01 = wx0 * fy, w11 = fx * fy;
    g[2 * l]     = w00 * f00.x + w10 * f10.x + w01 * f01.x + w11 * f11.x;
    g[2 * l + 1] = w00 * f00.y + w10 * f10.y + w01 * f01.y + w11 * f11.y;
  }
}

__global__ void __launch_bounds__(256) k_hash(const float* __restrict__ bt,
                                              float* __restrict__ g)
{
  int n = blockIdx.x * 256 + threadIdx.x;
  float gl[32];
  hash_features(bt, n, gl);
  float4* go = (float4*)(g + (size_t)n * 32);
#pragma unroll
  for (int q = 0; q < 8; ++q)
    go[q] = make_float4(gl[4 * q], gl[4 * q + 1], gl[4 * q + 2], gl[4 * q + 3]);
}

template <int FUSED>
__global__ void __launch_bounds__(256) k_mlp(
    const float* __restrict__ ws, const float* __restrict__ bt,
    const float* __restrict__ bb0, const float* __restrict__ bb1,
    const float* __restrict__ bb2, float* __restrict__ out)
{
  int tg = blockIdx.x * 256 + threadIdx.x;
  int b = tg >> 16;        // block-uniform
  int n = tg & 65535;

  float h[32];
  if constexpr (FUSED) {
    hash_features(bt, n, h);
  } else {
    const float4* gp = (const float4*)(ws + 51200 + (size_t)n * 32);
#pragma unroll
    for (int q = 0; q < 8; ++q) {
      float4 v = gp[q];
      h[4 * q] = v.x; h[4 * q + 1] = v.y; h[4 * q + 2] = v.z; h[4 * q + 3] = v.w;
    }
  }

  const float* __restrict__ W0 = ws + b * 2048;          // [j][i<32]
  const float* __restrict__ W1 = ws + 16384 + b * 4096;  // [j][i<64]
  const float* __restrict__ W2 = ws + 49152 + b * 256;   // [c][i<64]

  float a0[64];
#pragma unroll
  for (int jg = 0; jg < 16; ++jg) {
    float acc0 = bb0[4 * jg], acc1 = bb0[4 * jg + 1];
    float acc2 = bb0[4 * jg + 2], acc3 = bb0[4 * jg + 3];
#pragma unroll
    for (int i = 0; i < 32; ++i) {
      float hv = h[i];
      acc0 = fmaf(hv, W0[(4 * jg + 0) * 32 + i], acc0);
      acc1 = fmaf(hv, W0[(4 * jg + 1) * 32 + i], acc1);
      acc2 = fmaf(hv, W0[(4 * jg + 2) * 32 + i], acc2);
      acc3 = fmaf(hv, W0[(4 * jg + 3) * 32 + i], acc3);
    }
    a0[4 * jg] = lrelu(acc0); a0[4 * jg + 1] = lrelu(acc1);
    a0[4 * jg + 2] = lrelu(acc2); a0[4 * jg + 3] = lrelu(acc3);
  }

  float a1[64];
#pragma unroll
  for (int jg = 0; jg < 16; ++jg) {
    float acc0 = bb1[4 * jg], acc1 = bb1[4 * jg + 1];
    float acc2 = bb1[4 * jg + 2], acc3 = bb1[4 * jg + 3];
#pragma unroll
    for (int i = 0; i < 64; ++i) {
      float av = a0[i];
      acc0 = fmaf(av, W1[(4 * jg + 0) * 64 + i], acc0);
      acc1 = fmaf(av, W1[(4 * jg + 1) * 64 + i], acc1);
      acc2 = fmaf(av, W1[(4 * jg + 2) * 64 + i], acc2);
      acc3 = fmaf(av, W1[(4 * jg + 3) * 64 + i], acc3);
    }
    a1[4 * jg] = lrelu(acc0); a1[4 * jg + 1] = lrelu(acc1);
    a1[4 * jg + 2] = lrelu(acc2); a1[4 * jg + 3] = lrelu(acc3);
  }

#pragma unroll
  for (int c = 0; c < 3; ++c) {
    float acc = bb2[c];
#pragma unroll
    for (int i = 0; i < 64; ++i) acc = fmaf(a1[i], W2[c * 64 + i], acc);
    out[((b * 3 + c) << 16) + n] = tanhf(acc);
  }
}

extern "C" void kernel_launch(void* const* d_in, const int* in_sizes, int n_in,
                              void* d_out, int out_size, void* d_ws, size_t ws_size,
                              hipStream_t stream)
{
  const float* z    = (const float*)d_in[0];
  const float* mw0  = (const float*)d_in[1];
  const float* mb0  = (const float*)d_in[2];
  const float* mw1  = (const float*)d_in[3];
  const float* mb1  = (const float*)d_in[4];
  const float* mw2  = (const float*)d_in[5];
  const float* mb2  = (const float*)d_in[6];
  const float* bt   = (const float*)d_in[7];   // base_tables
  const float* wmod = (const float*)d_in[8];
  const float* bmod = (const float*)d_in[9];
  const float* a0w  = (const float*)d_in[10];
  const float* a0b  = (const float*)d_in[11];
  const float* w0   = (const float*)d_in[12];
  const float* bb0  = (const float*)d_in[13];
  const float* a1w  = (const float*)d_in[14];
  const float* a1b  = (const float*)d_in[15];
  const float* w1   = (const float*)d_in[16];
  const float* bb1  = (const float*)d_in[17];
  const float* a2w  = (const float*)d_in[18];
  const float* a2b  = (const float*)d_in[19];
  const float* w2   = (const float*)d_in[20];
  const float* bb2  = (const float*)d_in[21];
  float* ws  = (float*)d_ws;
  float* out = (float*)d_out;

  k_setup<<<1, 1024, 0, stream>>>(z, mw0, mb0, mw1, mb1, mw2, mb2,
                                  wmod, bmod, a0w, a0b, w0,
                                  a1w, a1b, w1, a2w, a2b, w2, ws);

  const size_t need_bytes = (size_t)(51200 + 65536 * 32) * 4;
  if (ws_size >= need_bytes) {
    k_hash<<<256, 256, 0, stream>>>(bt, ws + 51200);
    k_mlp<0><<<2048, 256, 0, stream>>>(ws, bt, bb0, bb1, bb2, out);
  } else {
    k_mlp<1><<<2048, 256, 0, stream>>>(ws, bt, bb0, bb1, bb2, out);
  }
}

// Round 2
// 355.809 us; speedup vs baseline: 1.8244x; 1.8244x over previous
//
#include <hip/hip_runtime.h>
#include <hip/hip_bf16.h>

#define NLVL 16
#define TSZ  16384
#define ZDIM 512
#define SDIM 256
#define IMG  256
#define HID  64
#define FDIM 32
#define NB   8

// floor(16 * exp(l*ln(16)/15)) computed with exact fp64 rounding analysis:
// l=15 lands at 255.99999999999997 -> 255 (NOT 256).
__device__ constexpr float RES_TAB[16] = {
  16.f, 19.f, 23.f, 27.f, 33.f, 40.f, 48.f, 58.f,
  70.f, 84.f, 101.f, 122.f, 147.f, 176.f, 212.f, 255.f
};

__device__ __forceinline__ float lrelu(float x) {
  float v = x < 0.0f ? 0.2f * x : x;
  return 1.41421356237309515f * v;  // GAIN * where(x>=0, x, 0.2x)
}

// ws layout (floats):
//   [0      .. 16384)  W0T[b][j<64][i<32]  (scale*style0*w0*demod0 folded)
//   [16384  .. 49152)  W1T[b][j<64][i<64]
//   [49152  .. 51200)  W2T[b][c<4][i<64]   (c==3 row zero-padded)
//   [51200  .. 51200+65536*32)  g[n][32]   (batch-independent hash features)

__global__ void __launch_bounds__(1024) k_setup(
    const float* __restrict__ z,
    const float* __restrict__ mw0, const float* __restrict__ mb0,
    const float* __restrict__ mw1, const float* __restrict__ mb1,
    const float* __restrict__ mw2, const float* __restrict__ mb2,
    const float* __restrict__ w_mod, const float* __restrict__ b_mod,
    const float* __restrict__ a0w, const float* __restrict__ a0b,
    const float* __restrict__ w0,
    const float* __restrict__ a1w, const float* __restrict__ a1b,
    const float* __restrict__ w1,
    const float* __restrict__ a2w, const float* __restrict__ a2b,
    const float* __restrict__ w2,
    float* __restrict__ ws)
{
  __shared__ float zs[NB][ZDIM];        // 16 KB
  __shared__ float sA[NB][SDIM];        // 8 KB
  __shared__ float sB[NB][SDIM];        // 8 KB
  __shared__ float st0[NB][FDIM], scf[NB][FDIM];
  __shared__ float st1[NB][HID], st2[NB][HID];
  __shared__ float dm0[NB][HID], dm1[NB][HID], dm2[NB][4];

  const int t = threadIdx.x;

  for (int k = t; k < NB * ZDIM; k += 1024) zs[k >> 9][k & 511] = z[k];
  __syncthreads();

  // mapping layer 0: z(8x512) @ mw0(512x256) + mb0, lrelu
  {
    int j = t & 255, bq = t >> 8;
    int b0 = 2 * bq, b1 = 2 * bq + 1;
    float acc0 = mb0[j], acc1 = acc0;
    for (int k = 0; k < ZDIM; ++k) {
      float w = mw0[k * SDIM + j];
      acc0 = fmaf(zs[b0][k], w, acc0);
      acc1 = fmaf(zs[b1][k], w, acc1);
    }
    sA[b0][j] = lrelu(acc0);
    sA[b1][j] = lrelu(acc1);
  }
  __syncthreads();
  // mapping layer 1
  {
    int j = t & 255, bq = t >> 8;
    int b0 = 2 * bq, b1 = 2 * bq + 1;
    float acc0 = mb1[j], acc1 = acc0;
    for (int k = 0; k < SDIM; ++k) {
      float w = mw1[k * SDIM + j];
      acc0 = fmaf(sA[b0][k], w, acc0);
      acc1 = fmaf(sA[b1][k], w, acc1);
    }
    sB[b0][j] = lrelu(acc0);
    sB[b1][j] = lrelu(acc1);
  }
  __syncthreads();
  // mapping layer 2 -> s in sA
  {
    int j = t & 255, bq = t >> 8;
    int b0 = 2 * bq, b1 = 2 * bq + 1;
    float acc0 = mb2[j], acc1 = acc0;
    for (int k = 0; k < SDIM; ++k) {
      float w = mw2[k * SDIM + j];
      acc0 = fmaf(sB[b0][k], w, acc0);
      acc1 = fmaf(sB[b1][k], w, acc1);
    }
    sA[b0][j] = lrelu(acc0);
    sA[b1][j] = lrelu(acc1);
  }
  __syncthreads();

  // scale (1 + s@w_mod + b_mod) and style0 (s@a0w + a0b): 8*32 entries
  if (t < 256) {
    int b = t >> 5, i = t & 31;
    float am = b_mod[i], as = a0b[i];
    for (int k = 0; k < SDIM; ++k) {
      float sv = sA[b][k];
      am = fmaf(sv, w_mod[k * FDIM + i], am);
      as = fmaf(sv, a0w[k * FDIM + i], as);
    }
    scf[b][i] = 1.0f + am;
    st0[b][i] = as;
  }
  // style1, style2: 8*64 entries
  if (t < 512) {
    int b = t >> 6, j = t & 63;
    float v1 = a1b[j], v2 = a2b[j];
    for (int k = 0; k < SDIM; ++k) {
      float sv = sA[b][k];
      v1 = fmaf(sv, a1w[k * HID + j], v1);
      v2 = fmaf(sv, a2w[k * HID + j], v2);
    }
    st1[b][j] = v1;
    st2[b][j] = v2;
  }
  __syncthreads();

  // demods: rsqrt(sum_i (style_i*w_ij)^2 + 1e-8)
  if (t < 512) {
    int b = t >> 6, j = t & 63;
    float acc = 1e-8f;
    for (int i = 0; i < FDIM; ++i) { float p = st0[b][i] * w0[i * HID + j]; acc = fmaf(p, p, acc); }
    dm0[b][j] = 1.0f / sqrtf(acc);
    float ac1 = 1e-8f;
    for (int i = 0; i < HID; ++i) { float p = st1[b][i] * w1[i * HID + j]; ac1 = fmaf(p, p, ac1); }
    dm1[b][j] = 1.0f / sqrtf(ac1);
  }
  if (t < 32) {
    int b = t >> 2, c = t & 3;
    if (c < 3) {
      float acc = 1e-8f;
      for (int i = 0; i < HID; ++i) { float p = st2[b][i] * w2[i * 3 + c]; acc = fmaf(p, p, acc); }
      dm2[b][c] = 1.0f / sqrtf(acc);
    } else {
      dm2[b][c] = 0.0f;
    }
  }
  __syncthreads();

  // effective weights (transposed [out][in] rows, contiguous in input idx)
  for (int f = t; f < 16384; f += 1024) {
    int b = f >> 11, j = (f >> 5) & 63, i = f & 31;
    ws[f] = scf[b][i] * st0[b][i] * w0[i * HID + j] * dm0[b][j];
  }
  for (int f = t; f < 32768; f += 1024) {
    int b = f >> 12, j = (f >> 6) & 63, i = f & 63;
    ws[16384 + f] = st1[b][i] * w1[i * HID + j] * dm1[b][j];
  }
  for (int f = t; f < 2048; f += 1024) {
    int b = f >> 8, c = (f >> 6) & 3, i = f & 63;
    ws[49152 + f] = (c < 3) ? st2[b][i] * w2[i * 3 + c] * dm2[b][c] : 0.0f;
  }
}

// batch-independent hash-grid features for pixel n
__device__ __forceinline__ void hash_features(const float* __restrict__ bt,
                                              int n, float* g)
{
  const float inv = 1.0f / 256.0f;
  float cx = ((n >> 8) + 0.5f) * inv;
  float cy = ((n & 255) + 0.5f) * inv;
#pragma unroll
  for (int l = 0; l < NLVL; ++l) {
    float res = RES_TAB[l];
    float px = cx * res, py = cy * res;
    float fx0 = floorf(px), fy0 = floorf(py);
    float fx = px - fx0, fy = py - fy0;
    unsigned x0 = (unsigned)fx0, y0 = (unsigned)fy0;
    unsigned hy0 = y0 * 2654435761u;
    unsigned hy1 = (y0 + 1u) * 2654435761u;
    unsigned i00 = (x0 ^ hy0) & 16383u;
    unsigned i10 = ((x0 + 1u) ^ hy0) & 16383u;
    unsigned i01 = (x0 ^ hy1) & 16383u;
    unsigned i11 = ((x0 + 1u) ^ hy1) & 16383u;
    const float2* tb = (const float2*)(bt + (size_t)l * (TSZ * 2));
    float2 f00 = tb[i00], f10 = tb[i10], f01 = tb[i01], f11 = tb[i11];
    float wx0 = 1.0f - fx, wy0 = 1.0f - fy;
    float w00 = wx0 * wy0, w10 = fx * wy0, w01 = wx0 * fy, w11 = fx * fy;
    g[2 * l]     = w00 * f00.x + w10 * f10.x + w01 * f01.x + w11 * f11.x;
    g[2 * l + 1] = w00 * f00.y + w10 * f10.y + w01 * f01.y + w11 * f11.y;
  }
}

__global__ void __launch_bounds__(256) k_hash(const float* __restrict__ bt,
                                              float* __restrict__ g)
{
  int n = blockIdx.x * 256 + threadIdx.x;
  float gl[32];
  hash_features(bt, n, gl);
  float4* go = (float4*)(g + (size_t)n * 32);
#pragma unroll
  for (int q = 0; q < 8; ++q)
    go[q] = make_float4(gl[4 * q], gl[4 * q + 1], gl[4 * q + 2], gl[4 * q + 3]);
}

// grid = dim3(256, NB). b = blockIdx.y is STRUCTURALLY wave-uniform ->
// all weight addresses are uniform with compile-time offsets -> compiler
// emits s_load through the scalar cache; inner loop is v_fmac v, s, v.
template <int FUSED>
__global__ void __launch_bounds__(256) k_mlp(
    const float* __restrict__ ws, const float* __restrict__ bt,
    const float* __restrict__ bb0, const float* __restrict__ bb1,
    const float* __restrict__ bb2, float* __restrict__ out)
{
  const int n = blockIdx.x * 256 + threadIdx.x;
  const int b = blockIdx.y;   // uniform

  float h[32];
  if constexpr (FUSED) {
    hash_features(bt, n, h);
  } else {
    const float4* gp = (const float4*)(ws + 51200 + (size_t)n * 32);
#pragma unroll
    for (int q = 0; q < 8; ++q) {
      float4 v = gp[q];
      h[4 * q] = v.x; h[4 * q + 1] = v.y; h[4 * q + 2] = v.z; h[4 * q + 3] = v.w;
    }
  }

  const float* __restrict__ W0 = ws + (size_t)b * 2048;          // [j][i<32]
  const float* __restrict__ W1 = ws + 16384 + (size_t)b * 4096;  // [j][i<64]
  const float* __restrict__ W2 = ws + 49152 + (size_t)b * 256;   // [c][i<64]

  float a0[64];
#pragma unroll
  for (int jg = 0; jg < 16; ++jg) {
    float acc0 = bb0[4 * jg], acc1 = bb0[4 * jg + 1];
    float acc2 = bb0[4 * jg + 2], acc3 = bb0[4 * jg + 3];
#pragma unroll
    for (int i = 0; i < 32; ++i) {
      float hv = h[i];
      acc0 = fmaf(hv, W0[(4 * jg + 0) * 32 + i], acc0);
      acc1 = fmaf(hv, W0[(4 * jg + 1) * 32 + i], acc1);
      acc2 = fmaf(hv, W0[(4 * jg + 2) * 32 + i], acc2);
      acc3 = fmaf(hv, W0[(4 * jg + 3) * 32 + i], acc3);
    }
    a0[4 * jg] = lrelu(acc0); a0[4 * jg + 1] = lrelu(acc1);
    a0[4 * jg + 2] = lrelu(acc2); a0[4 * jg + 3] = lrelu(acc3);
  }

  float a1[64];
#pragma unroll
  for (int jg = 0; jg < 16; ++jg) {
    float acc0 = bb1[4 * jg], acc1 = bb1[4 * jg + 1];
    float acc2 = bb1[4 * jg + 2], acc3 = bb1[4 * jg + 3];
#pragma unroll
    for (int i = 0; i < 64; ++i) {
      float av = a0[i];
      acc0 = fmaf(av, W1[(4 * jg + 0) * 64 + i], acc0);
      acc1 = fmaf(av, W1[(4 * jg + 1) * 64 + i], acc1);
      acc2 = fmaf(av, W1[(4 * jg + 2) * 64 + i], acc2);
      acc3 = fmaf(av, W1[(4 * jg + 3) * 64 + i], acc3);
    }
    a1[4 * jg] = lrelu(acc0); a1[4 * jg + 1] = lrelu(acc1);
    a1[4 * jg + 2] = lrelu(acc2); a1[4 * jg + 3] = lrelu(acc3);
  }

#pragma unroll
  for (int c = 0; c < 3; ++c) {
    float acc = bb2[c];
#pragma unroll
    for (int i = 0; i < 64; ++i) acc = fmaf(a1[i], W2[c * 64 + i], acc);
    out[((b * 3 + c) << 16) + n] = tanhf(acc);
  }
}

extern "C" void kernel_launch(void* const* d_in, const int* in_sizes, int n_in,
                              void* d_out, int out_size, void* d_ws, size_t ws_size,
                              hipStream_t stream)
{
  const float* z    = (const float*)d_in[0];
  const float* mw0  = (const float*)d_in[1];
  const float* mb0  = (const float*)d_in[2];
  const float* mw1  = (const float*)d_in[3];
  const float* mb1  = (const float*)d_in[4];
  const float* mw2  = (const float*)d_in[5];
  const float* mb2  = (const float*)d_in[6];
  const float* bt   = (const float*)d_in[7];   // base_tables
  const float* wmod = (const float*)d_in[8];
  const float* bmod = (const float*)d_in[9];
  const float* a0w  = (const float*)d_in[10];
  const float* a0b  = (const float*)d_in[11];
  const float* w0   = (const float*)d_in[12];
  const float* bb0  = (const float*)d_in[13];
  const float* a1w  = (const float*)d_in[14];
  const float* a1b  = (const float*)d_in[15];
  const float* w1   = (const float*)d_in[16];
  const float* bb1  = (const float*)d_in[17];
  const float* a2w  = (const float*)d_in[18];
  const float* a2b  = (const float*)d_in[19];
  const float* w2   = (const float*)d_in[20];
  const float* bb2  = (const float*)d_in[21];
  float* ws  = (float*)d_ws;
  float* out = (float*)d_out;

  k_setup<<<1, 1024, 0, stream>>>(z, mw0, mb0, mw1, mb1, mw2, mb2,
                                  wmod, bmod, a0w, a0b, w0,
                                  a1w, a1b, w1, a2w, a2b, w2, ws);

  const size_t need_bytes = (size_t)(51200 + 65536 * 32) * 4;
  if (ws_size >= need_bytes) {
    k_hash<<<256, 256, 0, stream>>>(bt, ws + 51200);
    k_mlp<0><<<dim3(256, NB), 256, 0, stream>>>(ws, bt, bb0, bb1, bb2, out);
  } else {
    k_mlp<1><<<dim3(256, NB), 256, 0, stream>>>(ws, bt, bb0, bb1, bb2, out);
  }
}

// Round 3
// 71.405 us; speedup vs baseline: 9.0911x; 4.9830x over previous
//
#include <hip/hip_runtime.h>
#include <hip/hip_bf16.h>

#define NLVL 16
#define TSZ  16384
#define IMG  256
#define NB   8

typedef _Float16 h8 __attribute__((ext_vector_type(8)));
typedef float    f4 __attribute__((ext_vector_type(4)));

#define MFMA16(A,B,C) __builtin_amdgcn_mfma_f32_16x16x32_f16(A,B,C,0,0,0)

// floor(16 * exp(l*ln(16)/15)); fp64 rounding analysis: l=15 -> 255 (NOT 256).
__device__ constexpr float RES_TAB[16] = {
  16.f, 19.f, 23.f, 27.f, 33.f, 40.f, 48.f, 58.f,
  70.f, 84.f, 101.f, 122.f, 147.f, 176.f, 212.f, 255.f
};

__device__ __forceinline__ float lrelu(float x) {
  float v = x < 0.0f ? 0.2f * x : x;
  return 1.41421356237309515f * v;
}

// ---------------- mapping MLP: one layer per launch, grid(8) x 256 ----------
__global__ void __launch_bounds__(256) k_map(
    const float* __restrict__ x, int K,
    const float* __restrict__ w, const float* __restrict__ bias,
    float* __restrict__ y)
{
  __shared__ float xs[512];
  const int b = blockIdx.x, j = threadIdx.x;
  for (int k = threadIdx.x; k < K; k += 256) xs[k] = x[b * K + k];
  __syncthreads();
  float acc = bias[j];
#pragma unroll 8
  for (int k = 0; k < K; ++k) acc = fmaf(xs[k], w[k * 256 + j], acc);
  y[b * 256 + j] = lrelu(acc);
}

// ---------------- fold styles/demod/scale into f16 weights ------------------
// W0h[b][j<64][i<32], W1h[b][j2<64][k<64], W2h[b][ch<16][k<64] (ch>=3 zero)
__global__ void __launch_bounds__(256) k_fold(
    const float* __restrict__ s,
    const float* __restrict__ w_mod, const float* __restrict__ b_mod,
    const float* __restrict__ a0w, const float* __restrict__ a0b,
    const float* __restrict__ w0,
    const float* __restrict__ a1w, const float* __restrict__ a1b,
    const float* __restrict__ w1,
    const float* __restrict__ a2w, const float* __restrict__ a2b,
    const float* __restrict__ w2,
    _Float16* __restrict__ W0h, _Float16* __restrict__ W1h,
    _Float16* __restrict__ W2h)
{
  __shared__ float ss[256];
  __shared__ float st0[32], scf[32], st1[64], st2[64];
  __shared__ float dm0[64], dm1[64], dm2[3];
  const int b = blockIdx.x, t = threadIdx.x;
  ss[t] = s[b * 256 + t];
  __syncthreads();
  if (t < 32) {
    float as = a0b[t], am = b_mod[t];
    for (int k = 0; k < 256; ++k) {
      float sv = ss[k];
      as = fmaf(sv, a0w[k * 32 + t], as);
      am = fmaf(sv, w_mod[k * 32 + t], am);
    }
    st0[t] = as; scf[t] = 1.0f + am;
  }
  if (t >= 64 && t < 128) {
    int j = t - 64; float v = a1b[j];
    for (int k = 0; k < 256; ++k) v = fmaf(ss[k], a1w[k * 64 + j], v);
    st1[j] = v;
  }
  if (t >= 128 && t < 192) {
    int j = t - 128; float v = a2b[j];
    for (int k = 0; k < 256; ++k) v = fmaf(ss[k], a2w[k * 64 + j], v);
    st2[j] = v;
  }
  __syncthreads();
  if (t < 64) {
    float acc = 1e-8f;
    for (int i = 0; i < 32; ++i) { float p = st0[i] * w0[i * 64 + t]; acc = fmaf(p, p, acc); }
    dm0[t] = 1.0f / sqrtf(acc);
  }
  if (t >= 64 && t < 128) {
    int j = t - 64; float acc = 1e-8f;
    for (int k = 0; k < 64; ++k) { float p = st1[k] * w1[k * 64 + j]; acc = fmaf(p, p, acc); }
    dm1[j] = 1.0f / sqrtf(acc);
  }
  if (t >= 192 && t < 195) {
    int ch = t - 192; float acc = 1e-8f;
    for (int k = 0; k < 64; ++k) { float p = st2[k] * w2[k * 3 + ch]; acc = fmaf(p, p, acc); }
    dm2[ch] = 1.0f / sqrtf(acc);
  }
  __syncthreads();
  for (int f = t; f < 2048; f += 256) {
    int j = f >> 5, i = f & 31;
    W0h[b * 2048 + f] = (_Float16)(scf[i] * st0[i] * w0[i * 64 + j] * dm0[j]);
  }
  for (int f = t; f < 4096; f += 256) {
    int j2 = f >> 6, k = f & 63;
    W1h[b * 4096 + f] = (_Float16)(st1[k] * w1[k * 64 + j2] * dm1[j2]);
  }
  for (int f = t; f < 1024; f += 256) {
    int ch = f >> 6, k = f & 63;
    W2h[b * 1024 + f] = (ch < 3) ? (_Float16)(st2[k] * w2[k * 3 + ch] * dm2[ch])
                                 : (_Float16)0.0f;
  }
}

// ---------------- hash-grid features (batch-independent) --------------------
__device__ __forceinline__ void hash_features(const float* __restrict__ bt,
                                              int n, float* g)
{
  const float inv = 1.0f / 256.0f;
  float cx = ((n >> 8) + 0.5f) * inv;
  float cy = ((n & 255) + 0.5f) * inv;
#pragma unroll
  for (int l = 0; l < NLVL; ++l) {
    float res = RES_TAB[l];
    float px = cx * res, py = cy * res;
    float fx0 = floorf(px), fy0 = floorf(py);
    float fx = px - fx0, fy = py - fy0;
    unsigned x0 = (unsigned)fx0, y0 = (unsigned)fy0;
    unsigned hy0 = y0 * 2654435761u;
    unsigned hy1 = (y0 + 1u) * 2654435761u;
    unsigned i00 = (x0 ^ hy0) & 16383u;
    unsigned i10 = ((x0 + 1u) ^ hy0) & 16383u;
    unsigned i01 = (x0 ^ hy1) & 16383u;
    unsigned i11 = ((x0 + 1u) ^ hy1) & 16383u;
    const float2* tb = (const float2*)(bt + (size_t)l * (TSZ * 2));
    float2 f00 = tb[i00], f10 = tb[i10], f01 = tb[i01], f11 = tb[i11];
    float wx0 = 1.0f - fx, wy0 = 1.0f - fy;
    float w00 = wx0 * wy0, w10 = fx * wy0, w01 = wx0 * fy, w11 = fx * fy;
    g[2 * l]     = w00 * f00.x + w10 * f10.x + w01 * f01.x + w11 * f11.x;
    g[2 * l + 1] = w00 * f00.y + w10 * f10.y + w01 * f01.y + w11 * f11.y;
  }
}

__global__ void __launch_bounds__(256) k_hash(const float* __restrict__ bt,
                                              _Float16* __restrict__ gh)
{
  int n = blockIdx.x * 256 + threadIdx.x;
  float gl[32];
  hash_features(bt, n, gl);
  union { _Float16 h[8]; uint4 u; } U;
  uint4* go = (uint4*)(gh + (size_t)n * 32);
#pragma unroll
  for (int q = 0; q < 4; ++q) {
#pragma unroll
    for (int e = 0; e < 8; ++e) U.h[e] = (_Float16)gl[q * 8 + e];
    go[q] = U.u;
  }
}

// ---------------- LDS activation staging helpers ----------------------------
// Layout per wave: [64 pix][64 k] halves, k XOR-swizzled by (pix&7)<<3
// (bits 3..5 only -> b64 4-packs and b128 8-frags stay contiguous).
__device__ __forceinline__ unsigned pk2(float a, float b) {
  union { _Float16 h[2]; unsigned u; } U;
  U.h[0] = (_Float16)a; U.h[1] = (_Float16)b;
  return U.u;
}
__device__ __forceinline__ void st4(_Float16* L, int pix, int jb, f4 v) {
  int ks = jb ^ ((pix & 7) << 3);
  *(uint2*)(L + pix * 64 + ks) = make_uint2(pk2(v[0], v[1]), pk2(v[2], v[3]));
}
__device__ __forceinline__ h8 ldf(const _Float16* L, int pix, int kb) {
  int ks = kb ^ ((pix & 7) << 3);
  return *(const h8*)(L + pix * 64 + ks);
}

// ---------------- MFMA MLP ---------------------------------------------------
// grid(256, 8) x 256. Per wave: 64 pixels. All layers computed TRANSPOSED:
// D^T[j][pix] = W_fold[j][k] (A operand, global f16) * act^T[k][pix] (B).
// C/D: col=lane&15 (=pix), row=(lane>>4)*4+reg (=j, 4 consecutive -> b64 pack).
template <int FUSED>
__global__ void __launch_bounds__(256) k_mlp(
    const _Float16* __restrict__ W0h, const _Float16* __restrict__ W1h,
    const _Float16* __restrict__ W2h, const _Float16* __restrict__ gh,
    const float* __restrict__ bt,
    const float* __restrict__ bb0, const float* __restrict__ bb1,
    const float* __restrict__ bb2, float* __restrict__ out)
{
  __shared__ _Float16 lds[4][4096];          // 8 KB per wave
  __shared__ _Float16 hb[FUSED ? 256 * 32 : 8];

  const int t = threadIdx.x;
  const int w = t >> 6, lane = t & 63;
  const int c = lane & 15, g = lane >> 4;
  const int b = blockIdx.y;
  const int pixb = blockIdx.x * 256 + w * 64;
  _Float16* L = lds[w];

  if constexpr (FUSED) {
    float gl[32];
    hash_features(bt, blockIdx.x * 256 + t, gl);
    union { _Float16 h[8]; uint4 u; } U;
#pragma unroll
    for (int q = 0; q < 4; ++q) {
#pragma unroll
      for (int e = 0; e < 8; ++e) U.h[e] = (_Float16)gl[q * 8 + e];
      *(uint4*)(hb + t * 32 + q * 8) = U.u;
    }
    __syncthreads();
  }

  // ---- preload weight A-frags (held whole kernel) ----
  h8 A0[4], A1[4][2], A2[2];
#pragma unroll
  for (int jt = 0; jt < 4; ++jt)
    A0[jt] = *(const h8*)&W0h[b * 2048 + (jt * 16 + c) * 32 + 8 * g];
#pragma unroll
  for (int jt = 0; jt < 4; ++jt)
#pragma unroll
    for (int kf = 0; kf < 2; ++kf)
      A1[jt][kf] = *(const h8*)&W1h[b * 4096 + (jt * 16 + c) * 64 + kf * 32 + 8 * g];
#pragma unroll
  for (int kf = 0; kf < 2; ++kf)
    A2[kf] = *(const h8*)&W2h[b * 1024 + c * 64 + kf * 32 + 8 * g];

  // biases: C-init rows = output channel = jt*16 + 4g + reg
  f4 bv0[4], bv1[4], bv2;
#pragma unroll
  for (int jt = 0; jt < 4; ++jt) {
    bv0[jt] = *(const f4*)&bb0[jt * 16 + 4 * g];
    bv1[jt] = *(const f4*)&bb1[jt * 16 + 4 * g];
  }
  if (g == 0) { bv2 = f4{bb2[0], bb2[1], bb2[2], 0.0f}; }
  else        { bv2 = f4{0.0f, 0.0f, 0.0f, 0.0f}; }

  // ---- layer 0: D0T[j][pix] = W0h[j][i] * h^T[i][pix] ----
  f4 acc[4][4];
#pragma unroll
  for (int pt = 0; pt < 4; ++pt) {
    h8 Bh;
    if constexpr (FUSED) {
      Bh = *(const h8*)&hb[(w * 64 + pt * 16 + c) * 32 + 8 * g];
    } else {
      Bh = *(const h8*)&gh[(size_t)(pixb + pt * 16 + c) * 32 + 8 * g];
    }
#pragma unroll
    for (int jt = 0; jt < 4; ++jt)
      acc[jt][pt] = MFMA16(A0[jt], Bh, bv0[jt]);
  }

  // lrelu + stage a0 into LDS
#pragma unroll
  for (int jt = 0; jt < 4; ++jt)
#pragma unroll
    for (int pt = 0; pt < 4; ++pt) {
      f4 v = acc[jt][pt];
#pragma unroll
      for (int r = 0; r < 4; ++r) v[r] = lrelu(v[r]);
      st4(L, pt * 16 + c, jt * 16 + 4 * g, v);
    }

  // ---- layer 1: D1T[j2][pix] = W1h[j2][k] * a0T[k][pix] ----
  f4 acc1[4][4];
#pragma unroll
  for (int pt = 0; pt < 4; ++pt) {
    h8 Bf0 = ldf(L, pt * 16 + c, 0 * 32 + 8 * g);
    h8 Bf1 = ldf(L, pt * 16 + c, 1 * 32 + 8 * g);
#pragma unroll
    for (int jt = 0; jt < 4; ++jt) {
      f4 a = MFMA16(A1[jt][0], Bf0, bv1[jt]);
      acc1[jt][pt] = MFMA16(A1[jt][1], Bf1, a);
    }
  }

  // lrelu + stage a1 (reuse same LDS region; all reads above are done)
#pragma unroll
  for (int jt = 0; jt < 4; ++jt)
#pragma unroll
    for (int pt = 0; pt < 4; ++pt) {
      f4 v = acc1[jt][pt];
#pragma unroll
      for (int r = 0; r < 4; ++r) v[r] = lrelu(v[r]);
      st4(L, pt * 16 + c, jt * 16 + 4 * g, v);
    }

  // ---- layer 2: D2T[ch][pix], ch = 4g + reg (only g==0, reg<3 real) ----
#pragma unroll
  for (int pt = 0; pt < 4; ++pt) {
    h8 Bf0 = ldf(L, pt * 16 + c, 0 * 32 + 8 * g);
    h8 Bf1 = ldf(L, pt * 16 + c, 1 * 32 + 8 * g);
    f4 a = MFMA16(A2[0], Bf0, bv2);
    a = MFMA16(A2[1], Bf1, a);
    if (g == 0) {
      int pix = pixb + pt * 16 + c;
#pragma unroll
      for (int r = 0; r < 3; ++r)
        out[((b * 3 + r) << 16) + pix] = tanhf(a[r]);
    }
  }
}

// ---------------- launch -----------------------------------------------------
// ws byte layout:
//   [0,8192)        s0 (f32 8x256)
//   [8192,16384)    s1
//   [16384,24576)   s2
//   [24576,57344)   W0h (f16 8x64x32)
//   [57344,122880)  W1h (f16 8x64x64)
//   [122880,139264) W2h (f16 8x16x64)
//   [139264,4333568) gh (f16 65536x32)
extern "C" void kernel_launch(void* const* d_in, const int* in_sizes, int n_in,
                              void* d_out, int out_size, void* d_ws, size_t ws_size,
                              hipStream_t stream)
{
  const float* z    = (const float*)d_in[0];
  const float* mw0  = (const float*)d_in[1];
  const float* mb0  = (const float*)d_in[2];
  const float* mw1  = (const float*)d_in[3];
  const float* mb1  = (const float*)d_in[4];
  const float* mw2  = (const float*)d_in[5];
  const float* mb2  = (const float*)d_in[6];
  const float* bt   = (const float*)d_in[7];
  const float* wmod = (const float*)d_in[8];
  const float* bmod = (const float*)d_in[9];
  const float* a0w  = (const float*)d_in[10];
  const float* a0b  = (const float*)d_in[11];
  const float* w0   = (const float*)d_in[12];
  const float* bb0  = (const float*)d_in[13];
  const float* a1w  = (const float*)d_in[14];
  const float* a1b  = (const float*)d_in[15];
  const float* w1   = (const float*)d_in[16];
  const float* bb1  = (const float*)d_in[17];
  const float* a2w  = (const float*)d_in[18];
  const float* a2b  = (const float*)d_in[19];
  const float* w2   = (const float*)d_in[20];
  const float* bb2  = (const float*)d_in[21];

  char* ws = (char*)d_ws;
  float*     s0  = (float*)(ws);
  float*     s1  = (float*)(ws + 8192);
  float*     s2  = (float*)(ws + 16384);
  _Float16*  W0h = (_Float16*)(ws + 24576);
  _Float16*  W1h = (_Float16*)(ws + 57344);
  _Float16*  W2h = (_Float16*)(ws + 122880);
  _Float16*  gh  = (_Float16*)(ws + 139264);
  float* out = (float*)d_out;

  k_map<<<NB, 256, 0, stream>>>(z, 512, mw0, mb0, s0);
  k_map<<<NB, 256, 0, stream>>>(s0, 256, mw1, mb1, s1);
  k_map<<<NB, 256, 0, stream>>>(s1, 256, mw2, mb2, s2);
  k_fold<<<NB, 256, 0, stream>>>(s2, wmod, bmod, a0w, a0b, w0,
                                 a1w, a1b, w1, a2w, a2b, w2, W0h, W1h, W2h);

  if (ws_size >= (size_t)4333568) {
    k_hash<<<256, 256, 0, stream>>>(bt, gh);
    k_mlp<0><<<dim3(256, NB), 256, 0, stream>>>(W0h, W1h, W2h, gh, bt,
                                                bb0, bb1, bb2, out);
  } else {
    k_mlp<1><<<dim3(256, NB), 256, 0, stream>>>(W0h, W1h, W2h, gh, bt,
                                                bb0, bb1, bb2, out);
  }
}

// Round 5
// 49.819 us; speedup vs baseline: 13.0300x; 1.4333x over previous
//
#include <hip/hip_runtime.h>
#include <hip/hip_bf16.h>

#define NLVL 16
#define TSZ  16384
#define NB   8

typedef _Float16 h8 __attribute__((ext_vector_type(8)));
typedef float    f4 __attribute__((ext_vector_type(4)));

#define MFMA16(A,B,C) __builtin_amdgcn_mfma_f32_16x16x32_f16(A,B,C,0,0,0)
#define GAINF 1.41421356237309515f

// floor(16 * exp(l*ln(16)/15)); fp64 rounding analysis: l=15 -> 255 (NOT 256).
__device__ constexpr float RES_TAB[16] = {
  16.f, 19.f, 23.f, 27.f, 33.f, 40.f, 48.f, 58.f,
  70.f, 84.f, 101.f, 122.f, 147.f, 176.f, 212.f, 255.f
};

__device__ __forceinline__ float lrelu(float x) {
  float v = x < 0.0f ? 0.2f * x : x;
  return GAINF * v;
}
// GAIN folded into the NEXT layer's weights -> activation is just max(x,0.2x)
__device__ __forceinline__ float act(float x) { return fmaxf(x, 0.2f * x); }

// tanh(x) = 1 - 2/(e^{2x}+1); exp2-based, 2 trans ops. x->+inf -> 1, -inf -> -1.
__device__ __forceinline__ float tanh_fast(float x) {
  float t = __builtin_amdgcn_exp2f(x * 2.8853900817779268f);  // e^{2x}
  return 1.0f - 2.0f * __builtin_amdgcn_rcpf(t + 1.0f);
}

__device__ __forceinline__ unsigned pk(float a, float b) {
  union { decltype(__builtin_amdgcn_cvt_pkrtz(0.f, 0.f)) h; unsigned u; } U;
  U.h = __builtin_amdgcn_cvt_pkrtz(a, b);
  return U.u;
}

// ---------------- hash-grid features (batch-independent) --------------------
__device__ __forceinline__ void hash_features(const float* __restrict__ bt,
                                              int n, float* g)
{
  const float inv = 1.0f / 256.0f;
  float cx = ((n >> 8) + 0.5f) * inv;
  float cy = ((n & 255) + 0.5f) * inv;
#pragma unroll
  for (int l = 0; l < NLVL; ++l) {
    float res = RES_TAB[l];
    float px = cx * res, py = cy * res;
    float fx0 = floorf(px), fy0 = floorf(py);
    float fx = px - fx0, fy = py - fy0;
    unsigned x0 = (unsigned)fx0, y0 = (unsigned)fy0;
    unsigned hy0 = y0 * 2654435761u;
    unsigned hy1 = (y0 + 1u) * 2654435761u;
    unsigned i00 = (x0 ^ hy0) & 16383u;
    unsigned i10 = ((x0 + 1u) ^ hy0) & 16383u;
    unsigned i01 = (x0 ^ hy1) & 16383u;
    unsigned i11 = ((x0 + 1u) ^ hy1) & 16383u;
    const float2* tb = (const float2*)(bt + (size_t)l * (TSZ * 2));
    float2 f00 = tb[i00], f10 = tb[i10], f01 = tb[i01], f11 = tb[i11];
    float wx0 = 1.0f - fx, wy0 = 1.0f - fy;
    float w00 = wx0 * wy0, w10 = fx * wy0, w01 = wx0 * fy, w11 = fx * fy;
    g[2 * l]     = w00 * f00.x + w10 * f10.x + w01 * f01.x + w11 * f11.x;
    g[2 * l + 1] = w00 * f00.y + w10 * f10.y + w01 * f01.y + w11 * f11.y;
  }
}

// ---------------- fused pre-pass ---------------------------------------------
// grid(8 + 256) x 256:
//   blocks 0..7   : mapping MLP (3 layers) + style/demod/scale fold, b = blockIdx.x
//   blocks 8..263 : hash features -> ghf in B-frag-major layout [tile][lane][8]
__global__ void __launch_bounds__(256) k_pre(
    const float* __restrict__ z,
    const float* __restrict__ mw0, const float* __restrict__ mb0,
    const float* __restrict__ mw1, const float* __restrict__ mb1,
    const float* __restrict__ mw2, const float* __restrict__ mb2,
    const float* __restrict__ bt,
    const float* __restrict__ w_mod, const float* __restrict__ b_mod,
    const float* __restrict__ a0w, const float* __restrict__ a0b,
    const float* __restrict__ w0,
    const float* __restrict__ a1w, const float* __restrict__ a1b,
    const float* __restrict__ w1,
    const float* __restrict__ a2w, const float* __restrict__ a2b,
    const float* __restrict__ w2,
    _Float16* __restrict__ W0h, _Float16* __restrict__ W1h,
    _Float16* __restrict__ W2h, _Float16* __restrict__ ghf)
{
  __shared__ float xs[512];   // z, then reused as s (final style)
  __shared__ float sA[256], sB[256];
  __shared__ float st0[32], scf[32], st1[64], st2[64];
  __shared__ float dm0[64], dm1[64], dm2[3];

  const int t = threadIdx.x;

  if (blockIdx.x >= 8) {
    // ---------------- hash part ----------------
    int n = (blockIdx.x - 8) * 256 + t;
    float gl[32];
    hash_features(bt, n, gl);
    int tile = n >> 4, c = n & 15;
#pragma unroll
    for (int gg = 0; gg < 4; ++gg) {
      union { unsigned u[4]; uint4 v; } U;
      U.u[0] = pk(gl[8 * gg + 0], gl[8 * gg + 1]);
      U.u[1] = pk(gl[8 * gg + 2], gl[8 * gg + 3]);
      U.u[2] = pk(gl[8 * gg + 4], gl[8 * gg + 5]);
      U.u[3] = pk(gl[8 * gg + 6], gl[8 * gg + 7]);
      *(uint4*)&ghf[(size_t)tile * 512 + (gg * 16 + c) * 8] = U.v;
    }
    return;
  }

  // ---------------- style + fold part ----------------
  const int b = blockIdx.x;

  for (int k = t; k < 512; k += 256) xs[k] = z[b * 512 + k];
  __syncthreads();
  {
    float a0 = 0, a1 = 0, a2 = 0, a3 = 0;
    for (int k = 0; k < 512; k += 4) {
      a0 = fmaf(xs[k + 0], mw0[(k + 0) * 256 + t], a0);
      a1 = fmaf(xs[k + 1], mw0[(k + 1) * 256 + t], a1);
      a2 = fmaf(xs[k + 2], mw0[(k + 2) * 256 + t], a2);
      a3 = fmaf(xs[k + 3], mw0[(k + 3) * 256 + t], a3);
    }
    sA[t] = lrelu(mb0[t] + ((a0 + a1) + (a2 + a3)));
  }
  __syncthreads();
  {
    float a0 = 0, a1 = 0, a2 = 0, a3 = 0;
    for (int k = 0; k < 256; k += 4) {
      a0 = fmaf(sA[k + 0], mw1[(k + 0) * 256 + t], a0);
      a1 = fmaf(sA[k + 1], mw1[(k + 1) * 256 + t], a1);
      a2 = fmaf(sA[k + 2], mw1[(k + 2) * 256 + t], a2);
      a3 = fmaf(sA[k + 3], mw1[(k + 3) * 256 + t], a3);
    }
    sB[t] = lrelu(mb1[t] + ((a0 + a1) + (a2 + a3)));
  }
  __syncthreads();
  {
    float a0 = 0, a1 = 0, a2 = 0, a3 = 0;
    for (int k = 0; k < 256; k += 4) {
      a0 = fmaf(sB[k + 0], mw2[(k + 0) * 256 + t], a0);
      a1 = fmaf(sB[k + 1], mw2[(k + 1) * 256 + t], a1);
      a2 = fmaf(sB[k + 2], mw2[(k + 2) * 256 + t], a2);
      a3 = fmaf(sB[k + 3], mw2[(k + 3) * 256 + t], a3);
    }
    xs[t] = lrelu(mb2[t] + ((a0 + a1) + (a2 + a3)));   // xs[0..255] = s
  }
  __syncthreads();
  const float* ss = xs;

  if (t < 32) {
    float as = a0b[t], am = b_mod[t];
    for (int k = 0; k < 256; ++k) {
      float sv = ss[k];
      as = fmaf(sv, a0w[k * 32 + t], as);
      am = fmaf(sv, w_mod[k * 32 + t], am);
    }
    st0[t] = as; scf[t] = 1.0f + am;
  }
  if (t >= 64 && t < 128) {
    int j = t - 64; float v = a1b[j];
    for (int k = 0; k < 256; ++k) v = fmaf(ss[k], a1w[k * 64 + j], v);
    st1[j] = v;
  }
  if (t >= 128 && t < 192) {
    int j = t - 128; float v = a2b[j];
    for (int k = 0; k < 256; ++k) v = fmaf(ss[k], a2w[k * 64 + j], v);
    st2[j] = v;
  }
  __syncthreads();
  if (t < 64) {
    float acc = 1e-8f;
    for (int i = 0; i < 32; ++i) { float p = st0[i] * w0[i * 64 + t]; acc = fmaf(p, p, acc); }
    dm0[t] = 1.0f / sqrtf(acc);
  }
  if (t >= 64 && t < 128) {
    int j = t - 64; float acc = 1e-8f;
    for (int k = 0; k < 64; ++k) { float p = st1[k] * w1[k * 64 + j]; acc = fmaf(p, p, acc); }
    dm1[j] = 1.0f / sqrtf(acc);
  }
  if (t >= 192 && t < 195) {
    int ch = t - 192; float acc = 1e-8f;
    for (int k = 0; k < 64; ++k) { float p = st2[k] * w2[k * 3 + ch]; acc = fmaf(p, p, acc); }
    dm2[ch] = 1.0f / sqrtf(acc);
  }
  __syncthreads();

  // W0h[j<64][i<32]; W1h[j2<64][k<64] x GAIN; W2h[ch<16][k<64] x GAIN
  for (int f = t; f < 2048; f += 256) {
    int j = f >> 5, i = f & 31;
    W0h[b * 2048 + f] = (_Float16)(scf[i] * st0[i] * w0[i * 64 + j] * dm0[j]);
  }
  for (int f = t; f < 4096; f += 256) {
    int j2 = f >> 6, k = f & 63;
    W1h[b * 4096 + f] = (_Float16)(GAINF * st1[k] * w1[k * 64 + j2] * dm1[j2]);
  }
  for (int f = t; f < 1024; f += 256) {
    int ch = f >> 6, k = f & 63;
    W2h[b * 1024 + f] = (ch < 3) ? (_Float16)(GAINF * st2[k] * w2[k * 3 + ch] * dm2[ch])
                                 : (_Float16)0.0f;
  }
}

// ---------------- LDS activation staging helpers ----------------------------
// Per wave [64 pix][64 k] halves, k XOR-swizzled by (pix&7)<<3.
__device__ __forceinline__ void st4(_Float16* L, int pix, int jb, f4 v) {
  int ks = jb ^ ((pix & 7) << 3);
  union { unsigned u[2]; uint2 v2; } U;
  U.u[0] = pk(v[0], v[1]); U.u[1] = pk(v[2], v[3]);
  *(uint2*)(L + pix * 64 + ks) = U.v2;
}
__device__ __forceinline__ h8 ldf(const _Float16* L, int pix, int kb) {
  int ks = kb ^ ((pix & 7) << 3);
  return *(const h8*)(L + pix * 64 + ks);
}

// ---------------- MFMA MLP ---------------------------------------------------
// grid(256, 8) x 256. Per wave: 64 pixels, transposed layers:
// D^T[j][pix] = W[j][k] (A) * act^T[k][pix] (B).
template <int FUSED>
__global__ void __launch_bounds__(256) k_mlp(
    const _Float16* __restrict__ W0h, const _Float16* __restrict__ W1h,
    const _Float16* __restrict__ W2h, const _Float16* __restrict__ ghf,
    const float* __restrict__ bt,
    const float* __restrict__ bb0, const float* __restrict__ bb1,
    const float* __restrict__ bb2, float* __restrict__ out)
{
  __shared__ _Float16 lds[4][4096];          // 8 KB per wave
  __shared__ _Float16 hb[FUSED ? 8192 : 8];

  const int t = threadIdx.x;
  const int w = t >> 6, lane = t & 63;
  const int c = lane & 15, g = lane >> 4;
  const int b = blockIdx.y;
  const int pixb = blockIdx.x * 256 + w * 64;
  const int tile0 = pixb >> 4;
  _Float16* L = lds[w];

  if constexpr (FUSED) {
    float gl[32];
    hash_features(bt, blockIdx.x * 256 + t, gl);
    int tl = t >> 4, cl = t & 15;
#pragma unroll
    for (int gg = 0; gg < 4; ++gg) {
      union { unsigned u[4]; uint4 v; } U;
      U.u[0] = pk(gl[8 * gg + 0], gl[8 * gg + 1]);
      U.u[1] = pk(gl[8 * gg + 2], gl[8 * gg + 3]);
      U.u[2] = pk(gl[8 * gg + 4], gl[8 * gg + 5]);
      U.u[3] = pk(gl[8 * gg + 6], gl[8 * gg + 7]);
      *(uint4*)&hb[tl * 512 + (gg * 16 + cl) * 8] = U.v;
    }
    __syncthreads();
  }

  // ---- preload weight A-frags ----
  h8 A0[4], A1[4][2], A2[2];
#pragma unroll
  for (int jt = 0; jt < 4; ++jt)
    A0[jt] = *(const h8*)&W0h[b * 2048 + (jt * 16 + c) * 32 + 8 * g];
#pragma unroll
  for (int jt = 0; jt < 4; ++jt)
#pragma unroll
    for (int kf = 0; kf < 2; ++kf)
      A1[jt][kf] = *(const h8*)&W1h[b * 4096 + (jt * 16 + c) * 64 + kf * 32 + 8 * g];
#pragma unroll
  for (int kf = 0; kf < 2; ++kf)
    A2[kf] = *(const h8*)&W2h[b * 1024 + c * 64 + kf * 32 + 8 * g];

  f4 bv0[4], bv1[4], bv2;
#pragma unroll
  for (int jt = 0; jt < 4; ++jt) {
    bv0[jt] = *(const f4*)&bb0[jt * 16 + 4 * g];
    bv1[jt] = *(const f4*)&bb1[jt * 16 + 4 * g];
  }
  if (g == 0) { bv2 = f4{bb2[0], bb2[1], bb2[2], 0.0f}; }
  else        { bv2 = f4{0.0f, 0.0f, 0.0f, 0.0f}; }

  // ---- layer 0 ----
  f4 acc[4][4];
#pragma unroll
  for (int pt = 0; pt < 4; ++pt) {
    h8 Bh;
    if constexpr (FUSED) {
      Bh = *(const h8*)&hb[(w * 4 + pt) * 512 + lane * 8];
    } else {
      Bh = *(const h8*)&ghf[(size_t)(tile0 + pt) * 512 + lane * 8];
    }
#pragma unroll
    for (int jt = 0; jt < 4; ++jt)
      acc[jt][pt] = MFMA16(A0[jt], Bh, bv0[jt]);
  }

#pragma unroll
  for (int jt = 0; jt < 4; ++jt)
#pragma unroll
    for (int pt = 0; pt < 4; ++pt) {
      f4 v = acc[jt][pt];
#pragma unroll
      for (int r = 0; r < 4; ++r) v[r] = act(v[r]);
      st4(L, pt * 16 + c, jt * 16 + 4 * g, v);
    }

  // ---- layer 1 ----
  f4 acc1[4][4];
#pragma unroll
  for (int pt = 0; pt < 4; ++pt) {
    h8 Bf0 = ldf(L, pt * 16 + c, 0 * 32 + 8 * g);
    h8 Bf1 = ldf(L, pt * 16 + c, 1 * 32 + 8 * g);
#pragma unroll
    for (int jt = 0; jt < 4; ++jt) {
      f4 a = MFMA16(A1[jt][0], Bf0, bv1[jt]);
      acc1[jt][pt] = MFMA16(A1[jt][1], Bf1, a);
    }
  }

#pragma unroll
  for (int jt = 0; jt < 4; ++jt)
#pragma unroll
    for (int pt = 0; pt < 4; ++pt) {
      f4 v = acc1[jt][pt];
#pragma unroll
      for (int r = 0; r < 4; ++r) v[r] = act(v[r]);
      st4(L, pt * 16 + c, jt * 16 + 4 * g, v);
    }

  // ---- layer 2 + tanh + store ----
#pragma unroll
  for (int pt = 0; pt < 4; ++pt) {
    h8 Bf0 = ldf(L, pt * 16 + c, 0 * 32 + 8 * g);
    h8 Bf1 = ldf(L, pt * 16 + c, 1 * 32 + 8 * g);
    f4 a = MFMA16(A2[0], Bf0, bv2);
    a = MFMA16(A2[1], Bf1, a);
    if (g == 0) {
      int pix = pixb + pt * 16 + c;
#pragma unroll
      for (int r = 0; r < 3; ++r)
        out[((b * 3 + r) << 16) + pix] = tanh_fast(a[r]);
    }
  }
}

// ---------------- launch -----------------------------------------------------
// ws byte layout:
//   [0,32768)          W0h (f16 8x64x32)
//   [32768,98304)      W1h (f16 8x64x64)
//   [98304,114688)     W2h (f16 8x16x64)
//   [114688,4308992)   ghf (f16 65536x32, frag-major [tile][lane][8])
extern "C" void kernel_launch(void* const* d_in, const int* in_sizes, int n_in,
                              void* d_out, int out_size, void* d_ws, size_t ws_size,
                              hipStream_t stream)
{
  const float* z    = (const float*)d_in[0];
  const float* mw0  = (const float*)d_in[1];
  const float* mb0  = (const float*)d_in[2];
  const float* mw1  = (const float*)d_in[3];
  const float* mb1  = (const float*)d_in[4];
  const float* mw2  = (const float*)d_in[5];
  const float* mb2  = (const float*)d_in[6];
  const float* bt   = (const float*)d_in[7];
  const float* wmod = (const float*)d_in[8];
  const float* bmod = (const float*)d_in[9];
  const float* a0w  = (const float*)d_in[10];
  const float* a0b  = (const float*)d_in[11];
  const float* w0   = (const float*)d_in[12];
  const float* bb0  = (const float*)d_in[13];
  const float* a1w  = (const float*)d_in[14];
  const float* a1b  = (const float*)d_in[15];
  const float* w1   = (const float*)d_in[16];
  const float* bb1  = (const float*)d_in[17];
  const float* a2w  = (const float*)d_in[18];
  const float* a2b  = (const float*)d_in[19];
  const float* w2   = (const float*)d_in[20];
  const float* bb2  = (const float*)d_in[21];

  char* ws = (char*)d_ws;
  _Float16* W0h = (_Float16*)(ws);
  _Float16* W1h = (_Float16*)(ws + 32768);
  _Float16* W2h = (_Float16*)(ws + 98304);
  _Float16* ghf = (_Float16*)(ws + 114688);
  float* out = (float*)d_out;

  k_pre<<<8 + 256, 256, 0, stream>>>(z, mw0, mb0, mw1, mb1, mw2, mb2, bt,
                                     wmod, bmod, a0w, a0b, w0,
                                     a1w, a1b, w1, a2w, a2b, w2,
                                     W0h, W1h, W2h, ghf);

  if (ws_size >= (size_t)4308992) {
    k_mlp<0><<<dim3(256, NB), 256, 0, stream>>>(W0h, W1h, W2h, ghf, bt,
                                                bb0, bb1, bb2, out);
  } else {
    k_mlp<1><<<dim3(256, NB), 256, 0, stream>>>(W0h, W1h, W2h, ghf, bt,
                                                bb0, bb1, bb2, out);
  }
}

// Round 6
// 46.325 us; speedup vs baseline: 14.0129x; 1.0754x over previous
//
#include <hip/hip_runtime.h>
#include <hip/hip_bf16.h>

#define NLVL 16
#define TSZ  16384
#define NB   8

typedef _Float16 h8 __attribute__((ext_vector_type(8)));
typedef float    f4 __attribute__((ext_vector_type(4)));

#define MFMA16(A,B,C) __builtin_amdgcn_mfma_f32_16x16x32_f16(A,B,C,0,0,0)
#define GAINF 1.41421356237309515f

// floor(16 * exp(l*ln(16)/15)); fp64 rounding analysis: l=15 -> 255 (NOT 256).
__device__ constexpr float RES_TAB[16] = {
  16.f, 19.f, 23.f, 27.f, 33.f, 40.f, 48.f, 58.f,
  70.f, 84.f, 101.f, 122.f, 147.f, 176.f, 212.f, 255.f
};

__device__ __forceinline__ float lrelu(float x) {
  float v = x < 0.0f ? 0.2f * x : x;
  return GAINF * v;
}
// GAIN folded into the NEXT layer's weights -> activation is just max(x,0.2x)
__device__ __forceinline__ float act(float x) { return fmaxf(x, 0.2f * x); }

// tanh(x) = 1 - 2/(e^{2x}+1); exp2-based. x->+inf -> 1, -inf -> -1.
__device__ __forceinline__ float tanh_fast(float x) {
  float t = __builtin_amdgcn_exp2f(x * 2.8853900817779268f);  // e^{2x}
  return 1.0f - 2.0f * __builtin_amdgcn_rcpf(t + 1.0f);
}

__device__ __forceinline__ unsigned pk(float a, float b) {
  union { decltype(__builtin_amdgcn_cvt_pkrtz(0.f, 0.f)) h; unsigned u; } U;
  U.h = __builtin_amdgcn_cvt_pkrtz(a, b);
  return U.u;
}

// ---------------- hash-grid features (batch-independent) --------------------
__device__ __forceinline__ void hash_features(const float* __restrict__ bt,
                                              int n, float* g)
{
  const float inv = 1.0f / 256.0f;
  float cx = ((n >> 8) + 0.5f) * inv;
  float cy = ((n & 255) + 0.5f) * inv;
#pragma unroll
  for (int l = 0; l < NLVL; ++l) {
    float res = RES_TAB[l];
    float px = cx * res, py = cy * res;
    float fx0 = floorf(px), fy0 = floorf(py);
    float fx = px - fx0, fy = py - fy0;
    unsigned x0 = (unsigned)fx0, y0 = (unsigned)fy0;
    unsigned hy0 = y0 * 2654435761u;
    unsigned hy1 = (y0 + 1u) * 2654435761u;
    unsigned i00 = (x0 ^ hy0) & 16383u;
    unsigned i10 = ((x0 + 1u) ^ hy0) & 16383u;
    unsigned i01 = (x0 ^ hy1) & 16383u;
    unsigned i11 = ((x0 + 1u) ^ hy1) & 16383u;
    const float2* tb = (const float2*)(bt + (size_t)l * (TSZ * 2));
    float2 f00 = tb[i00], f10 = tb[i10], f01 = tb[i01], f11 = tb[i11];
    float wx0 = 1.0f - fx, wy0 = 1.0f - fy;
    float w00 = wx0 * wy0, w10 = fx * wy0, w01 = wx0 * fy, w11 = fx * fy;
    g[2 * l]     = w00 * f00.x + w10 * f10.x + w01 * f01.x + w11 * f11.x;
    g[2 * l + 1] = w00 * f00.y + w10 * f10.y + w01 * f01.y + w11 * f11.y;
  }
}

// ---------------- mapping layer: in-block split-K, float4 weight loads -------
// threads 256: ks = t>>6 (4 K-chunks), j4 = (t&63)*4 (4 output cols/thread).
// part = LDS float[4*256]. xs_in/out_lds must not alias.
__device__ __forceinline__ void map_layer(const float* __restrict__ xs_in,
                                          float* __restrict__ out_lds,
                                          const float* __restrict__ W,
                                          const float* __restrict__ bias,
                                          int K, int t,
                                          float* __restrict__ part)
{
  const int j4 = (t & 63) * 4;
  const int ks = t >> 6;
  const int chunk = K >> 2;
  const int kb = ks * chunk;
  f4 a0 = {0,0,0,0}, a1 = {0,0,0,0}, a2 = {0,0,0,0}, a3 = {0,0,0,0};
#pragma unroll 4
  for (int k = 0; k < chunk; k += 4) {
    f4 w0 = *(const f4*)&W[(kb + k + 0) * 256 + j4];
    f4 w1 = *(const f4*)&W[(kb + k + 1) * 256 + j4];
    f4 w2 = *(const f4*)&W[(kb + k + 2) * 256 + j4];
    f4 w3 = *(const f4*)&W[(kb + k + 3) * 256 + j4];
    float x0 = xs_in[kb + k + 0], x1 = xs_in[kb + k + 1];
    float x2 = xs_in[kb + k + 2], x3 = xs_in[kb + k + 3];
    a0 += x0 * w0; a1 += x1 * w1; a2 += x2 * w2; a3 += x3 * w3;
  }
  *(f4*)&part[ks * 256 + j4] = (a0 + a1) + (a2 + a3);
  __syncthreads();
  {
    float v = part[t] + part[256 + t] + part[512 + t] + part[768 + t];
    out_lds[t] = lrelu(bias[t] + v);
  }
  __syncthreads();
}

// ---------------- fused pre-pass ---------------------------------------------
// grid(8 + 256) x 256:
//   blocks 0..7   : mapping MLP (3 layers, split-K) + style/demod/scale fold
//   blocks 8..263 : hash features -> ghf in B-frag-major layout [tile][lane][8]
__global__ void __launch_bounds__(256) k_pre(
    const float* __restrict__ z,
    const float* __restrict__ mw0, const float* __restrict__ mb0,
    const float* __restrict__ mw1, const float* __restrict__ mb1,
    const float* __restrict__ mw2, const float* __restrict__ mb2,
    const float* __restrict__ bt,
    const float* __restrict__ w_mod, const float* __restrict__ b_mod,
    const float* __restrict__ a0w, const float* __restrict__ a0b,
    const float* __restrict__ w0,
    const float* __restrict__ a1w, const float* __restrict__ a1b,
    const float* __restrict__ w1,
    const float* __restrict__ a2w, const float* __restrict__ a2b,
    const float* __restrict__ w2,
    _Float16* __restrict__ W0h, _Float16* __restrict__ W1h,
    _Float16* __restrict__ W2h, _Float16* __restrict__ ghf)
{
  __shared__ float xs[512];   // z, then reused as s (final style)
  __shared__ float sA[256], sB[256];
  __shared__ float part[1024];
  __shared__ float st0[32], scf[32], st1[64], st2[64];
  __shared__ float dm0[64], dm1[64], dm2[3];

  const int t = threadIdx.x;

  if (blockIdx.x >= 8) {
    // ---------------- hash part ----------------
    int n = (blockIdx.x - 8) * 256 + t;
    float gl[32];
    hash_features(bt, n, gl);
    int tile = n >> 4, c = n & 15;
#pragma unroll
    for (int gg = 0; gg < 4; ++gg) {
      union { unsigned u[4]; uint4 v; } U;
      U.u[0] = pk(gl[8 * gg + 0], gl[8 * gg + 1]);
      U.u[1] = pk(gl[8 * gg + 2], gl[8 * gg + 3]);
      U.u[2] = pk(gl[8 * gg + 4], gl[8 * gg + 5]);
      U.u[3] = pk(gl[8 * gg + 6], gl[8 * gg + 7]);
      *(uint4*)&ghf[(size_t)tile * 512 + (gg * 16 + c) * 8] = U.v;
    }
    return;
  }

  // ---------------- style + fold part ----------------
  const int b = blockIdx.x;

  for (int k = t; k < 512; k += 256) xs[k] = z[b * 512 + k];
  __syncthreads();

  map_layer(xs, sA, mw0, mb0, 512, t, part);   // layer0: z -> sA
  map_layer(sA, sB, mw1, mb1, 256, t, part);   // layer1
  map_layer(sB, xs, mw2, mb2, 256, t, part);   // layer2 -> xs[0..255] = s
  const float* ss = xs;

  if (t < 32) {
    float as = a0b[t], am = b_mod[t];
    for (int k = 0; k < 256; ++k) {
      float sv = ss[k];
      as = fmaf(sv, a0w[k * 32 + t], as);
      am = fmaf(sv, w_mod[k * 32 + t], am);
    }
    st0[t] = as; scf[t] = 1.0f + am;
  }
  if (t >= 64 && t < 128) {
    int j = t - 64; float v = a1b[j];
    for (int k = 0; k < 256; ++k) v = fmaf(ss[k], a1w[k * 64 + j], v);
    st1[j] = v;
  }
  if (t >= 128 && t < 192) {
    int j = t - 128; float v = a2b[j];
    for (int k = 0; k < 256; ++k) v = fmaf(ss[k], a2w[k * 64 + j], v);
    st2[j] = v;
  }
  __syncthreads();
  if (t < 64) {
    float acc = 1e-8f;
    for (int i = 0; i < 32; ++i) { float p = st0[i] * w0[i * 64 + t]; acc = fmaf(p, p, acc); }
    dm0[t] = 1.0f / sqrtf(acc);
  }
  if (t >= 64 && t < 128) {
    int j = t - 64; float acc = 1e-8f;
    for (int k = 0; k < 64; ++k) { float p = st1[k] * w1[k * 64 + j]; acc = fmaf(p, p, acc); }
    dm1[j] = 1.0f / sqrtf(acc);
  }
  if (t >= 192 && t < 195) {
    int ch = t - 192; float acc = 1e-8f;
    for (int k = 0; k < 64; ++k) { float p = st2[k] * w2[k * 3 + ch]; acc = fmaf(p, p, acc); }
    dm2[ch] = 1.0f / sqrtf(acc);
  }
  __syncthreads();

  // W0h[j<64][i<32]; W1h[j2<64][k<64] x GAIN; W2h[ch<16][k<64] x GAIN
  for (int f = t; f < 2048; f += 256) {
    int j = f >> 5, i = f & 31;
    W0h[b * 2048 + f] = (_Float16)(scf[i] * st0[i] * w0[i * 64 + j] * dm0[j]);
  }
  for (int f = t; f < 4096; f += 256) {
    int j2 = f >> 6, k = f & 63;
    W1h[b * 4096 + f] = (_Float16)(GAINF * st1[k] * w1[k * 64 + j2] * dm1[j2]);
  }
  for (int f = t; f < 1024; f += 256) {
    int ch = f >> 6, k = f & 63;
    W2h[b * 1024 + f] = (ch < 3) ? (_Float16)(GAINF * st2[k] * w2[k * 3 + ch] * dm2[ch])
                                 : (_Float16)0.0f;
  }
}

// ---------------- LDS activation staging helpers ----------------------------
// Per wave [64 pix][64 k] halves, k XOR-swizzled by (pix&7)<<3.
__device__ __forceinline__ void st4(_Float16* L, int pix, int jb, f4 v) {
  int ks = jb ^ ((pix & 7) << 3);
  union { unsigned u[2]; uint2 v2; } U;
  U.u[0] = pk(v[0], v[1]); U.u[1] = pk(v[2], v[3]);
  *(uint2*)(L + pix * 64 + ks) = U.v2;
}
__device__ __forceinline__ h8 ldf(const _Float16* L, int pix, int kb) {
  int ks = kb ^ ((pix & 7) << 3);
  return *(const h8*)(L + pix * 64 + ks);
}

// ---------------- MFMA MLP ---------------------------------------------------
// grid(256, 8) x 256. Per wave: 64 pixels, transposed layers:
// D^T[j][pix] = W[j][k] (A) * act^T[k][pix] (B).
template <int FUSED>
__global__ void __launch_bounds__(256) k_mlp(
    const _Float16* __restrict__ W0h, const _Float16* __restrict__ W1h,
    const _Float16* __restrict__ W2h, const _Float16* __restrict__ ghf,
    const float* __restrict__ bt,
    const float* __restrict__ bb0, const float* __restrict__ bb1,
    const float* __restrict__ bb2, float* __restrict__ out)
{
  __shared__ _Float16 lds[4][4096];          // 8 KB per wave
  __shared__ _Float16 hb[FUSED ? 8192 : 8];

  const int t = threadIdx.x;
  const int w = t >> 6, lane = t & 63;
  const int c = lane & 15, g = lane >> 4;
  const int b = blockIdx.y;
  const int pixb = blockIdx.x * 256 + w * 64;
  const int tile0 = pixb >> 4;
  _Float16* L = lds[w];

  if constexpr (FUSED) {
    float gl[32];
    hash_features(bt, blockIdx.x * 256 + t, gl);
    int tl = t >> 4, cl = t & 15;
#pragma unroll
    for (int gg = 0; gg < 4; ++gg) {
      union { unsigned u[4]; uint4 v; } U;
      U.u[0] = pk(gl[8 * gg + 0], gl[8 * gg + 1]);
      U.u[1] = pk(gl[8 * gg + 2], gl[8 * gg + 3]);
      U.u[2] = pk(gl[8 * gg + 4], gl[8 * gg + 5]);
      U.u[3] = pk(gl[8 * gg + 6], gl[8 * gg + 7]);
      *(uint4*)&hb[tl * 512 + (gg * 16 + cl) * 8] = U.v;
    }
    __syncthreads();
  }

  // ---- preload weight A-frags ----
  h8 A0[4], A1[4][2], A2[2];
#pragma unroll
  for (int jt = 0; jt < 4; ++jt)
    A0[jt] = *(const h8*)&W0h[b * 2048 + (jt * 16 + c) * 32 + 8 * g];
#pragma unroll
  for (int jt = 0; jt < 4; ++jt)
#pragma unroll
    for (int kf = 0; kf < 2; ++kf)
      A1[jt][kf] = *(const h8*)&W1h[b * 4096 + (jt * 16 + c) * 64 + kf * 32 + 8 * g];
#pragma unroll
  for (int kf = 0; kf < 2; ++kf)
    A2[kf] = *(const h8*)&W2h[b * 1024 + c * 64 + kf * 32 + 8 * g];

  f4 bv0[4], bv1[4], bv2;
#pragma unroll
  for (int jt = 0; jt < 4; ++jt) {
    bv0[jt] = *(const f4*)&bb0[jt * 16 + 4 * g];
    bv1[jt] = *(const f4*)&bb1[jt * 16 + 4 * g];
  }
  if (g == 0) { bv2 = f4{bb2[0], bb2[1], bb2[2], 0.0f}; }
  else        { bv2 = f4{0.0f, 0.0f, 0.0f, 0.0f}; }

  // ---- layer 0 ----
  f4 acc[4][4];
#pragma unroll
  for (int pt = 0; pt < 4; ++pt) {
    h8 Bh;
    if constexpr (FUSED) {
      Bh = *(const h8*)&hb[(w * 4 + pt) * 512 + lane * 8];
    } else {
      Bh = *(const h8*)&ghf[(size_t)(tile0 + pt) * 512 + lane * 8];
    }
#pragma unroll
    for (int jt = 0; jt < 4; ++jt)
      acc[jt][pt] = MFMA16(A0[jt], Bh, bv0[jt]);
  }

#pragma unroll
  for (int jt = 0; jt < 4; ++jt)
#pragma unroll
    for (int pt = 0; pt < 4; ++pt) {
      f4 v = acc[jt][pt];
#pragma unroll
      for (int r = 0; r < 4; ++r) v[r] = act(v[r]);
      st4(L, pt * 16 + c, jt * 16 + 4 * g, v);
    }

  // ---- layer 1 ----
  f4 acc1[4][4];
#pragma unroll
  for (int pt = 0; pt < 4; ++pt) {
    h8 Bf0 = ldf(L, pt * 16 + c, 0 * 32 + 8 * g);
    h8 Bf1 = ldf(L, pt * 16 + c, 1 * 32 + 8 * g);
#pragma unroll
    for (int jt = 0; jt < 4; ++jt) {
      f4 a = MFMA16(A1[jt][0], Bf0, bv1[jt]);
      acc1[jt][pt] = MFMA16(A1[jt][1], Bf1, a);
    }
  }

#pragma unroll
  for (int jt = 0; jt < 4; ++jt)
#pragma unroll
    for (int pt = 0; pt < 4; ++pt) {
      f4 v = acc1[jt][pt];
#pragma unroll
      for (int r = 0; r < 4; ++r) v[r] = act(v[r]);
      st4(L, pt * 16 + c, jt * 16 + 4 * g, v);
    }

  // ---- layer 2 + tanh + store ----
#pragma unroll
  for (int pt = 0; pt < 4; ++pt) {
    h8 Bf0 = ldf(L, pt * 16 + c, 0 * 32 + 8 * g);
    h8 Bf1 = ldf(L, pt * 16 + c, 1 * 32 + 8 * g);
    f4 a = MFMA16(A2[0], Bf0, bv2);
    a = MFMA16(A2[1], Bf1, a);
    if (g == 0) {
      int pix = pixb + pt * 16 + c;
#pragma unroll
      for (int r = 0; r < 3; ++r)
        out[((b * 3 + r) << 16) + pix] = tanh_fast(a[r]);
    }
  }
}

// ---------------- launch -----------------------------------------------------
// ws byte layout:
//   [0,32768)          W0h (f16 8x64x32)
//   [32768,98304)      W1h (f16 8x64x64)
//   [98304,114688)     W2h (f16 8x16x64)
//   [114688,4308992)   ghf (f16 65536x32, frag-major [tile][lane][8])
extern "C" void kernel_launch(void* const* d_in, const int* in_sizes, int n_in,
                              void* d_out, int out_size, void* d_ws, size_t ws_size,
                              hipStream_t stream)
{
  const float* z    = (const float*)d_in[0];
  const float* mw0  = (const float*)d_in[1];
  const float* mb0  = (const float*)d_in[2];
  const float* mw1  = (const float*)d_in[3];
  const float* mb1  = (const float*)d_in[4];
  const float* mw2  = (const float*)d_in[5];
  const float* mb2  = (const float*)d_in[6];
  const float* bt   = (const float*)d_in[7];
  const float* wmod = (const float*)d_in[8];
  const float* bmod = (const float*)d_in[9];
  const float* a0w  = (const float*)d_in[10];
  const float* a0b  = (const float*)d_in[11];
  const float* w0   = (const float*)d_in[12];
  const float* bb0  = (const float*)d_in[13];
  const float* a1w  = (const float*)d_in[14];
  const float* a1b  = (const float*)d_in[15];
  const float* w1   = (const float*)d_in[16];
  const float* bb1  = (const float*)d_in[17];
  const float* a2w  = (const float*)d_in[18];
  const float* a2b  = (const float*)d_in[19];
  const float* w2   = (const float*)d_in[20];
  const float* bb2  = (const float*)d_in[21];

  char* ws = (char*)d_ws;
  _Float16* W0h = (_Float16*)(ws);
  _Float16* W1h = (_Float16*)(ws + 32768);
  _Float16* W2h = (_Float16*)(ws + 98304);
  _Float16* ghf = (_Float16*)(ws + 114688);
  float* out = (float*)d_out;

  k_pre<<<8 + 256, 256, 0, stream>>>(z, mw0, mb0, mw1, mb1, mw2, mb2, bt,
                                     wmod, bmod, a0w, a0b, w0,
                                     a1w, a1b, w1, a2w, a2b, w2,
                                     W0h, W1h, W2h, ghf);

  if (ws_size >= (size_t)4308992) {
    k_mlp<0><<<dim3(256, NB), 256, 0, stream>>>(W0h, W1h, W2h, ghf, bt,
                                                bb0, bb1, bb2, out);
  } else {
    k_mlp<1><<<dim3(256, NB), 256, 0, stream>>>(W0h, W1h, W2h, ghf, bt,
                                                bb0, bb1, bb2, out);
  }
}

// Round 7
// 45.324 us; speedup vs baseline: 14.3222x; 1.0221x over previous
//
#include <hip/hip_runtime.h>
#include <hip/hip_bf16.h>

#define NLVL 16
#define TSZ  16384
#define NB   8

typedef _Float16 h8 __attribute__((ext_vector_type(8)));
typedef float    f4 __attribute__((ext_vector_type(4)));

#define MFMA16(A,B,C) __builtin_amdgcn_mfma_f32_16x16x32_f16(A,B,C,0,0,0)
#define GAINF 1.41421356237309515f

// floor(16 * exp(l*ln(16)/15)); fp64 rounding analysis: l=15 -> 255 (NOT 256).
__device__ constexpr float RES_TAB[16] = {
  16.f, 19.f, 23.f, 27.f, 33.f, 40.f, 48.f, 58.f,
  70.f, 84.f, 101.f, 122.f, 147.f, 176.f, 212.f, 255.f
};

__device__ __forceinline__ float lrelu(float x) {
  float v = x < 0.0f ? 0.2f * x : x;
  return GAINF * v;
}
// GAIN folded into the NEXT layer's weights -> activation is just max(x,0.2x)
__device__ __forceinline__ float act(float x) { return fmaxf(x, 0.2f * x); }

// tanh(x) = 1 - 2/(e^{2x}+1); exp2-based. x->+inf -> 1, -inf -> -1.
__device__ __forceinline__ float tanh_fast(float x) {
  float t = __builtin_amdgcn_exp2f(x * 2.8853900817779268f);  // e^{2x}
  return 1.0f - 2.0f * __builtin_amdgcn_rcpf(t + 1.0f);
}

__device__ __forceinline__ unsigned pk(float a, float b) {
  union { decltype(__builtin_amdgcn_cvt_pkrtz(0.f, 0.f)) h; unsigned u; } U;
  U.h = __builtin_amdgcn_cvt_pkrtz(a, b);
  return U.u;
}

// ---------------- hash-grid features (batch-independent) --------------------
__device__ __forceinline__ void hash_features(const float* __restrict__ bt,
                                              int n, float* g)
{
  const float inv = 1.0f / 256.0f;
  float cx = ((n >> 8) + 0.5f) * inv;
  float cy = ((n & 255) + 0.5f) * inv;
#pragma unroll
  for (int l = 0; l < NLVL; ++l) {
    float res = RES_TAB[l];
    float px = cx * res, py = cy * res;
    float fx0 = floorf(px), fy0 = floorf(py);
    float fx = px - fx0, fy = py - fy0;
    unsigned x0 = (unsigned)fx0, y0 = (unsigned)fy0;
    unsigned hy0 = y0 * 2654435761u;
    unsigned hy1 = (y0 + 1u) * 2654435761u;
    unsigned i00 = (x0 ^ hy0) & 16383u;
    unsigned i10 = ((x0 + 1u) ^ hy0) & 16383u;
    unsigned i01 = (x0 ^ hy1) & 16383u;
    unsigned i11 = ((x0 + 1u) ^ hy1) & 16383u;
    const float2* tb = (const float2*)(bt + (size_t)l * (TSZ * 2));
    float2 f00 = tb[i00], f10 = tb[i10], f01 = tb[i01], f11 = tb[i11];
    float wx0 = 1.0f - fx, wy0 = 1.0f - fy;
    float w00 = wx0 * wy0, w10 = fx * wy0, w01 = wx0 * fy, w11 = fx * fy;
    g[2 * l]     = w00 * f00.x + w10 * f10.x + w01 * f01.x + w11 * f11.x;
    g[2 * l + 1] = w00 * f00.y + w10 * f10.y + w01 * f01.y + w11 * f11.y;
  }
}

// ---------------- L2 prefetch helper ----------------------------------------
// Pull slice s (of 32) of a weight array into this XCD's L2. Values sunk via
// asm to stay live (no DCE), never stored.
__device__ __forceinline__ void pf_slice(const float* __restrict__ p, int nf4,
                                         int s, int t, uint2& sink)
{
  int per = nf4 >> 5;
  const uint4* q = (const uint4*)p + (size_t)s * per;
  for (int e = t; e < per; e += 256) {
    uint4 v = q[e];
    sink.x ^= v.x; sink.y ^= v.w;
  }
}

// ---------------- mapping layer: in-block split-K, float4 weight loads -------
__device__ __forceinline__ void map_layer(const float* __restrict__ xs_in,
                                          float* __restrict__ out_lds,
                                          const float* __restrict__ W,
                                          const float* __restrict__ bias,
                                          int K, int t,
                                          float* __restrict__ part)
{
  const int j4 = (t & 63) * 4;
  const int ks = t >> 6;
  const int chunk = K >> 2;
  const int kb = ks * chunk;
  f4 a0 = {0,0,0,0}, a1 = {0,0,0,0}, a2 = {0,0,0,0}, a3 = {0,0,0,0};
#pragma unroll 4
  for (int k = 0; k < chunk; k += 4) {
    f4 w0 = *(const f4*)&W[(kb + k + 0) * 256 + j4];
    f4 w1 = *(const f4*)&W[(kb + k + 1) * 256 + j4];
    f4 w2 = *(const f4*)&W[(kb + k + 2) * 256 + j4];
    f4 w3 = *(const f4*)&W[(kb + k + 3) * 256 + j4];
    float x0 = xs_in[kb + k + 0], x1 = xs_in[kb + k + 1];
    float x2 = xs_in[kb + k + 2], x3 = xs_in[kb + k + 3];
    a0 += x0 * w0; a1 += x1 * w1; a2 += x2 * w2; a3 += x3 * w3;
  }
  *(f4*)&part[ks * 256 + j4] = (a0 + a1) + (a2 + a3);
  __syncthreads();
  {
    float v = part[t] + part[256 + t] + part[512 + t] + part[768 + t];
    out_lds[t] = lrelu(bias[t] + v);
  }
  __syncthreads();
}

// ---------------- fused pre-pass ---------------------------------------------
// grid(8 + 256) x 256:
//   blocks 0..7   : mapping MLP (split-K) + projections (split-K) + fold
//   blocks 8..263 : L2-prefetch weight slice (i>>3), then hash features -> ghf
__global__ void __launch_bounds__(256) k_pre(
    const float* __restrict__ z,
    const float* __restrict__ mw0, const float* __restrict__ mb0,
    const float* __restrict__ mw1, const float* __restrict__ mb1,
    const float* __restrict__ mw2, const float* __restrict__ mb2,
    const float* __restrict__ bt,
    const float* __restrict__ w_mod, const float* __restrict__ b_mod,
    const float* __restrict__ a0w, const float* __restrict__ a0b,
    const float* __restrict__ w0,
    const float* __restrict__ a1w, const float* __restrict__ a1b,
    const float* __restrict__ w1,
    const float* __restrict__ a2w, const float* __restrict__ a2b,
    const float* __restrict__ w2,
    _Float16* __restrict__ W0h, _Float16* __restrict__ W1h,
    _Float16* __restrict__ W2h, _Float16* __restrict__ ghf)
{
  __shared__ float xs[512];   // z, then reused as s (final style)
  __shared__ float sA[256], sB[256];
  __shared__ float part[1024];
  __shared__ float st0[32], scf[32], st1[64], st2[64];
  __shared__ float dm0[64], dm1[64], dm2[3];

  const int t = threadIdx.x;

  if (blockIdx.x >= 8) {
    // ---- L2 prefetch of style weights (slice per block; one copy per XCD
    //      under round-robin blockIdx->XCD dispatch) ----
    int s = (blockIdx.x - 8) >> 3;          // 0..31
    uint2 sink = {0, 0};
    pf_slice(mw0,  32768, s, t, sink);
    pf_slice(mw1,  16384, s, t, sink);
    pf_slice(mw2,  16384, s, t, sink);
    pf_slice(w_mod, 2048, s, t, sink);
    pf_slice(a0w,   2048, s, t, sink);
    pf_slice(a1w,   4096, s, t, sink);
    pf_slice(a2w,   4096, s, t, sink);
    pf_slice(w0,     512, s, t, sink);
    pf_slice(w1,    1024, s, t, sink);
    if (s == 0) {                            // w2 + biases (small)
      const uint4* q = (const uint4*)w2;
      for (int e = t; e < 48; e += 256) { uint4 v = q[e]; sink.x ^= v.x; }
      const uint4* qb = (const uint4*)mb0;
      for (int e = t; e < 64; e += 256) { uint4 v = qb[e]; sink.y ^= v.y; }
    }
    asm volatile("" :: "v"(sink.x), "v"(sink.y));

    // ---- hash part ----
    int n = (blockIdx.x - 8) * 256 + t;
    float gl[32];
    hash_features(bt, n, gl);
    int tile = n >> 4, c = n & 15;
#pragma unroll
    for (int gg = 0; gg < 4; ++gg) {
      union { unsigned u[4]; uint4 v; } U;
      U.u[0] = pk(gl[8 * gg + 0], gl[8 * gg + 1]);
      U.u[1] = pk(gl[8 * gg + 2], gl[8 * gg + 3]);
      U.u[2] = pk(gl[8 * gg + 4], gl[8 * gg + 5]);
      U.u[3] = pk(gl[8 * gg + 6], gl[8 * gg + 7]);
      *(uint4*)&ghf[(size_t)tile * 512 + (gg * 16 + c) * 8] = U.v;
    }
    return;
  }

  // ---------------- style + fold part ----------------
  const int b = blockIdx.x;

  for (int k = t; k < 512; k += 256) xs[k] = z[b * 512 + k];
  __syncthreads();

  map_layer(xs, sA, mw0, mb0, 512, t, part);   // layer0: z -> sA
  map_layer(sA, sB, mw1, mb1, 256, t, part);   // layer1
  map_layer(sB, xs, mw2, mb2, 256, t, part);   // layer2 -> xs[0..255] = s
  const float* ss = xs;

  // ---- projections, split-K across all 256 threads ----
  {  // [w_mod | a0w], N=32: j = t&31, 8 k-chunks of 32
    const int j = t & 31, kb = (t >> 5) * 32;
    float am = 0.f, as = 0.f;
#pragma unroll 8
    for (int k = 0; k < 32; ++k) {
      float sv = ss[kb + k];
      am = fmaf(sv, w_mod[(kb + k) * 32 + j], am);
      as = fmaf(sv, a0w[(kb + k) * 32 + j], as);
    }
    part[t] = am; part[256 + t] = as;
  }
  {  // [a1w | a2w], N=64: j = t&63, 4 k-chunks of 64
    const int j = t & 63, kb = (t >> 6) * 64;
    float v1 = 0.f, v2 = 0.f;
#pragma unroll 8
    for (int k = 0; k < 64; ++k) {
      float sv = ss[kb + k];
      v1 = fmaf(sv, a1w[(kb + k) * 64 + j], v1);
      v2 = fmaf(sv, a2w[(kb + k) * 64 + j], v2);
    }
    part[512 + t] = v1; part[768 + t] = v2;
  }
  __syncthreads();
  if (t < 32) {
    float am = b_mod[t], as = a0b[t];
#pragma unroll
    for (int q = 0; q < 8; ++q) { am += part[q * 32 + t]; as += part[256 + q * 32 + t]; }
    scf[t] = 1.0f + am; st0[t] = as;
  }
  if (t >= 128 && t < 192) {
    int j = t - 128;
    float v1 = a1b[j], v2 = a2b[j];
#pragma unroll
    for (int q = 0; q < 4; ++q) { v1 += part[512 + q * 64 + j]; v2 += part[768 + q * 64 + j]; }
    st1[j] = v1; st2[j] = v2;
  }
  __syncthreads();

  // ---- demods ----
  if (t < 64) {
    float acc = 1e-8f;
    for (int i = 0; i < 32; ++i) { float p = st0[i] * w0[i * 64 + t]; acc = fmaf(p, p, acc); }
    dm0[t] = 1.0f / sqrtf(acc);
  }
  if (t >= 64 && t < 128) {
    int j = t - 64; float acc = 1e-8f;
    for (int k = 0; k < 64; ++k) { float p = st1[k] * w1[k * 64 + j]; acc = fmaf(p, p, acc); }
    dm1[j] = 1.0f / sqrtf(acc);
  }
  if (t >= 192 && t < 195) {
    int ch = t - 192; float acc = 1e-8f;
    for (int k = 0; k < 64; ++k) { float p = st2[k] * w2[k * 3 + ch]; acc = fmaf(p, p, acc); }
    dm2[ch] = 1.0f / sqrtf(acc);
  }
  __syncthreads();

  // W0h[j<64][i<32]; W1h[j2<64][k<64] x GAIN; W2h[ch<16][k<64] x GAIN
  for (int f = t; f < 2048; f += 256) {
    int j = f >> 5, i = f & 31;
    W0h[b * 2048 + f] = (_Float16)(scf[i] * st0[i] * w0[i * 64 + j] * dm0[j]);
  }
  for (int f = t; f < 4096; f += 256) {
    int j2 = f >> 6, k = f & 63;
    W1h[b * 4096 + f] = (_Float16)(GAINF * st1[k] * w1[k * 64 + j2] * dm1[j2]);
  }
  for (int f = t; f < 1024; f += 256) {
    int ch = f >> 6, k = f & 63;
    W2h[b * 1024 + f] = (ch < 3) ? (_Float16)(GAINF * st2[k] * w2[k * 3 + ch] * dm2[ch])
                                 : (_Float16)0.0f;
  }
}

// ---------------- LDS activation staging helpers ----------------------------
// Per wave [64 pix][64 k] halves, k XOR-swizzled by (pix&7)<<3.
__device__ __forceinline__ void st4(_Float16* L, int pix, int jb, f4 v) {
  int ks = jb ^ ((pix & 7) << 3);
  union { unsigned u[2]; uint2 v2; } U;
  U.u[0] = pk(v[0], v[1]); U.u[1] = pk(v[2], v[3]);
  *(uint2*)(L + pix * 64 + ks) = U.v2;
}
__device__ __forceinline__ h8 ldf(const _Float16* L, int pix, int kb) {
  int ks = kb ^ ((pix & 7) << 3);
  return *(const h8*)(L + pix * 64 + ks);
}

// ---------------- MFMA MLP ---------------------------------------------------
// grid(256, 8) x 256. Per wave: 64 pixels, transposed layers:
// D^T[j][pix] = W[j][k] (A) * act^T[k][pix] (B).
template <int FUSED>
__global__ void __launch_bounds__(256) k_mlp(
    const _Float16* __restrict__ W0h, const _Float16* __restrict__ W1h,
    const _Float16* __restrict__ W2h, const _Float16* __restrict__ ghf,
    const float* __restrict__ bt,
    const float* __restrict__ bb0, const float* __restrict__ bb1,
    const float* __restrict__ bb2, float* __restrict__ out)
{
  __shared__ _Float16 lds[4][4096];          // 8 KB per wave
  __shared__ _Float16 hb[FUSED ? 8192 : 8];

  const int t = threadIdx.x;
  const int w = t >> 6, lane = t & 63;
  const int c = lane & 15, g = lane >> 4;
  const int b = blockIdx.y;
  const int pixb = blockIdx.x * 256 + w * 64;
  const int tile0 = pixb >> 4;
  _Float16* L = lds[w];

  if constexpr (FUSED) {
    float gl[32];
    hash_features(bt, blockIdx.x * 256 + t, gl);
    int tl = t >> 4, cl = t & 15;
#pragma unroll
    for (int gg = 0; gg < 4; ++gg) {
      union { unsigned u[4]; uint4 v; } U;
      U.u[0] = pk(gl[8 * gg + 0], gl[8 * gg + 1]);
      U.u[1] = pk(gl[8 * gg + 2], gl[8 * gg + 3]);
      U.u[2] = pk(gl[8 * gg + 4], gl[8 * gg + 5]);
      U.u[3] = pk(gl[8 * gg + 6], gl[8 * gg + 7]);
      *(uint4*)&hb[tl * 512 + (gg * 16 + cl) * 8] = U.v;
    }
    __syncthreads();
  }

  // ---- preload weight A-frags ----
  h8 A0[4], A1[4][2], A2[2];
#pragma unroll
  for (int jt = 0; jt < 4; ++jt)
    A0[jt] = *(const h8*)&W0h[b * 2048 + (jt * 16 + c) * 32 + 8 * g];
#pragma unroll
  for (int jt = 0; jt < 4; ++jt)
#pragma unroll
    for (int kf = 0; kf < 2; ++kf)
      A1[jt][kf] = *(const h8*)&W1h[b * 4096 + (jt * 16 + c) * 64 + kf * 32 + 8 * g];
#pragma unroll
  for (int kf = 0; kf < 2; ++kf)
    A2[kf] = *(const h8*)&W2h[b * 1024 + c * 64 + kf * 32 + 8 * g];

  f4 bv0[4], bv1[4], bv2;
#pragma unroll
  for (int jt = 0; jt < 4; ++jt) {
    bv0[jt] = *(const f4*)&bb0[jt * 16 + 4 * g];
    bv1[jt] = *(const f4*)&bb1[jt * 16 + 4 * g];
  }
  if (g == 0) { bv2 = f4{bb2[0], bb2[1], bb2[2], 0.0f}; }
  else        { bv2 = f4{0.0f, 0.0f, 0.0f, 0.0f}; }

  // ---- layer 0 ----
  f4 acc[4][4];
#pragma unroll
  for (int pt = 0; pt < 4; ++pt) {
    h8 Bh;
    if constexpr (FUSED) {
      Bh = *(const h8*)&hb[(w * 4 + pt) * 512 + lane * 8];
    } else {
      Bh = *(const h8*)&ghf[(size_t)(tile0 + pt) * 512 + lane * 8];
    }
#pragma unroll
    for (int jt = 0; jt < 4; ++jt)
      acc[jt][pt] = MFMA16(A0[jt], Bh, bv0[jt]);
  }

#pragma unroll
  for (int jt = 0; jt < 4; ++jt)
#pragma unroll
    for (int pt = 0; pt < 4; ++pt) {
      f4 v = acc[jt][pt];
#pragma unroll
      for (int r = 0; r < 4; ++r) v[r] = act(v[r]);
      st4(L, pt * 16 + c, jt * 16 + 4 * g, v);
    }

  // ---- layer 1 ----
  f4 acc1[4][4];
#pragma unroll
  for (int pt = 0; pt < 4; ++pt) {
    h8 Bf0 = ldf(L, pt * 16 + c, 0 * 32 + 8 * g);
    h8 Bf1 = ldf(L, pt * 16 + c, 1 * 32 + 8 * g);
#pragma unroll
    for (int jt = 0; jt < 4; ++jt) {
      f4 a = MFMA16(A1[jt][0], Bf0, bv1[jt]);
      acc1[jt][pt] = MFMA16(A1[jt][1], Bf1, a);
    }
  }

#pragma unroll
  for (int jt = 0; jt < 4; ++jt)
#pragma unroll
    for (int pt = 0; pt < 4; ++pt) {
      f4 v = acc1[jt][pt];
#pragma unroll
      for (int r = 0; r < 4; ++r) v[r] = act(v[r]);
      st4(L, pt * 16 + c, jt * 16 + 4 * g, v);
    }

  // ---- layer 2 + tanh + store ----
#pragma unroll
  for (int pt = 0; pt < 4; ++pt) {
    h8 Bf0 = ldf(L, pt * 16 + c, 0 * 32 + 8 * g);
    h8 Bf1 = ldf(L, pt * 16 + c, 1 * 32 + 8 * g);
    f4 a = MFMA16(A2[0], Bf0, bv2);
    a = MFMA16(A2[1], Bf1, a);
    if (g == 0) {
      int pix = pixb + pt * 16 + c;
#pragma unroll
      for (int r = 0; r < 3; ++r)
        out[((b * 3 + r) << 16) + pix] = tanh_fast(a[r]);
    }
  }
}

// ---------------- launch -----------------------------------------------------
// ws byte layout:
//   [0,32768)          W0h (f16 8x64x32)
//   [32768,98304)      W1h (f16 8x64x64)
//   [98304,114688)     W2h (f16 8x16x64)
//   [114688,4308992)   ghf (f16 65536x32, frag-major [tile][lane][8])
extern "C" void kernel_launch(void* const* d_in, const int* in_sizes, int n_in,
                              void* d_out, int out_size, void* d_ws, size_t ws_size,
                              hipStream_t stream)
{
  const float* z    = (const float*)d_in[0];
  const float* mw0  = (const float*)d_in[1];
  const float* mb0  = (const float*)d_in[2];
  const float* mw1  = (const float*)d_in[3];
  const float* mb1  = (const float*)d_in[4];
  const float* mw2  = (const float*)d_in[5];
  const float* mb2  = (const float*)d_in[6];
  const float* bt   = (const float*)d_in[7];
  const float* wmod = (const float*)d_in[8];
  const float* bmod = (const float*)d_in[9];
  const float* a0w  = (const float*)d_in[10];
  const float* a0b  = (const float*)d_in[11];
  const float* w0   = (const float*)d_in[12];
  const float* bb0  = (const float*)d_in[13];
  const float* a1w  = (const float*)d_in[14];
  const float* a1b  = (const float*)d_in[15];
  const float* w1   = (const float*)d_in[16];
  const float* bb1  = (const float*)d_in[17];
  const float* a2w  = (const float*)d_in[18];
  const float* a2b  = (const float*)d_in[19];
  const float* w2   = (const float*)d_in[20];
  const float* bb2  = (const float*)d_in[21];

  char* ws = (char*)d_ws;
  _Float16* W0h = (_Float16*)(ws);
  _Float16* W1h = (_Float16*)(ws + 32768);
  _Float16* W2h = (_Float16*)(ws + 98304);
  _Float16* ghf = (_Float16*)(ws + 114688);
  float* out = (float*)d_out;

  k_pre<<<8 + 256, 256, 0, stream>>>(z, mw0, mb0, mw1, mb1, mw2, mb2, bt,
                                     wmod, bmod, a0w, a0b, w0,
                                     a1w, a1b, w1, a2w, a2b, w2,
                                     W0h, W1h, W2h, ghf);

  if (ws_size >= (size_t)4308992) {
    k_mlp<0><<<dim3(256, NB), 256, 0, stream>>>(W0h, W1h, W2h, ghf, bt,
                                                bb0, bb1, bb2, out);
  } else {
    k_mlp<1><<<dim3(256, NB), 256, 0, stream>>>(W0h, W1h, W2h, ghf, bt,
                                                bb0, bb1, bb2, out);
  }
}